// Round 2
// baseline (3986.096 us; speedup 1.0000x reference)
//
#include <hip/hip_runtime.h>
#include <hip/hip_bf16.h>

#define N_NODES 100000
#define N_EDGES 1600000
#define N_GRAPHS 64

// ---------------------------------------------------------------- CSR build
__global__ void k_count(const int* __restrict__ dst, int* __restrict__ count) {
    int e = blockIdx.x * blockDim.x + threadIdx.x;
    if (e < N_EDGES) atomicAdd(&count[dst[e]], 1);
}

// block-local exclusive scan, 1024 elems/block (256 thr x 4)
__global__ void k_scan1(const int* __restrict__ cnt, int* __restrict__ rs, int* __restrict__ partials) {
    __shared__ int s[256];
    int b = blockIdx.x, t = threadIdx.x;
    int base = b * 1024 + t * 4;
    int v0 = 0, v1 = 0, v2 = 0, v3 = 0;
    if (base + 3 < N_NODES) {
        int4 q = *(const int4*)(cnt + base);
        v0 = q.x; v1 = q.y; v2 = q.z; v3 = q.w;
    } else {
        if (base     < N_NODES) v0 = cnt[base];
        if (base + 1 < N_NODES) v1 = cnt[base + 1];
        if (base + 2 < N_NODES) v2 = cnt[base + 2];
        if (base + 3 < N_NODES) v3 = cnt[base + 3];
    }
    int tsum = v0 + v1 + v2 + v3;
    s[t] = tsum; __syncthreads();
    for (int off = 1; off < 256; off <<= 1) {
        int x = (t >= off) ? s[t - off] : 0;
        __syncthreads();
        s[t] += x;
        __syncthreads();
    }
    int excl = s[t] - tsum;
    if (base     < N_NODES) rs[base]     = excl;
    excl += v0;
    if (base + 1 < N_NODES) rs[base + 1] = excl;
    excl += v1;
    if (base + 2 < N_NODES) rs[base + 2] = excl;
    excl += v2;
    if (base + 3 < N_NODES) rs[base + 3] = excl;
    if (t == 255) partials[b] = s[255];
}

__global__ void k_scan2(int* __restrict__ partials, int nb) {
    __shared__ int s[128];
    int t = threadIdx.x;
    int v = (t < nb) ? partials[t] : 0;
    s[t] = v; __syncthreads();
    for (int off = 1; off < 128; off <<= 1) {
        int x = (t >= off) ? s[t - off] : 0;
        __syncthreads();
        s[t] += x;
        __syncthreads();
    }
    if (t < nb) partials[t] = s[t] - v;  // exclusive
}

__global__ void k_scan3(int* __restrict__ rs, int* __restrict__ cursor, const int* __restrict__ partials) {
    int b = blockIdx.x, t = threadIdx.x;
    int off = partials[b];
    int base = b * 1024 + t * 4;
#pragma unroll
    for (int i = 0; i < 4; ++i) {
        int idx = base + i;
        if (idx < N_NODES) {
            int v = rs[idx] + off;
            rs[idx] = v;
            cursor[idx] = v;
        }
    }
    if (b == 0 && t == 0) rs[N_NODES] = N_EDGES;
}

__global__ void k_invdeg(const int* __restrict__ count, const int* __restrict__ gid,
                         float* __restrict__ invdeg, float* __restrict__ cntg) {
    int v = blockIdx.x * blockDim.x + threadIdx.x;
    if (v >= N_NODES) return;
    int d = count[v];
    invdeg[v] = d > 0 ? 1.0f / (float)d : 0.0f;
    atomicAdd(&cntg[gid[v]], 1.0f);
}

__global__ void k_fill(const int* __restrict__ src, const int* __restrict__ dst,
                       int* __restrict__ cursor, int* __restrict__ csr) {
    int e = blockIdx.x * blockDim.x + threadIdx.x;
    if (e >= N_EDGES) return;
    int d = dst[e];
    int pos = atomicAdd(&cursor[d], 1);
    csr[pos] = src[e];
}

// ------------------------------------------------------- gather (wave/node)
// out[v][f] = invdeg[v] * sum_{e: dst=v} feat[src[e]][f],  F <= 128
__global__ void k_gather(const float* __restrict__ feat, float* __restrict__ out,
                         const int* __restrict__ csr, const int* __restrict__ rs,
                         const float* __restrict__ invdeg, int F) {
    int wid = (blockIdx.x * blockDim.x + threadIdx.x) >> 6;
    int lane = threadIdx.x & 63;
    if (wid >= N_NODES) return;
    int s0 = rs[wid], s1 = rs[wid + 1];
    int f1 = lane + 64;
    float acc0 = 0.f, acc1 = 0.f;
    for (int j = s0; j < s1; ++j) {
        int s = csr[j];
        const float* row = feat + (size_t)s * F;
        if (lane < F) acc0 += row[lane];
        if (f1 < F)   acc1 += row[f1];
    }
    float sc = invdeg[wid];
    float* orow = out + (size_t)wid * F;
    if (lane < F) orow[lane] = acc0 * sc;
    if (f1 < F)   orow[f1]   = acc1 * sc;
}

__global__ void k_gather5(const float* __restrict__ feat, float* __restrict__ out,
                          const int* __restrict__ csr, const int* __restrict__ rs,
                          const float* __restrict__ invdeg) {
    int v = blockIdx.x * blockDim.x + threadIdx.x;
    if (v >= N_NODES) return;
    int s0 = rs[v], s1 = rs[v + 1];
    float a0 = 0, a1 = 0, a2 = 0, a3 = 0, a4 = 0;
    for (int j = s0; j < s1; ++j) {
        const float* r = feat + (size_t)csr[j] * 5;
        a0 += r[0]; a1 += r[1]; a2 += r[2]; a3 += r[3]; a4 += r[4];
    }
    float sc = invdeg[v];
    float* o = out + (size_t)v * 5;
    o[0] = a0 * sc; o[1] = a1 * sc; o[2] = a2 * sc; o[3] = a3 * sc; o[4] = a4 * sc;
}

// ------------------------------------------------------------ fused fp32 GEMM
// C[M x N] = act( A1@W1 [+ A2@W2] [+ addend] [+ bias] )
// BM=64, BN=64, TK=16; 256 threads, each 4x4 outputs.
#define TK 16
__global__ __launch_bounds__(256) void k_gemm(
        const float* __restrict__ A1, const float* __restrict__ W1, int K1,
        const float* __restrict__ A2, const float* __restrict__ W2, int K2,
        const float* __restrict__ addend, const float* __restrict__ bias,
        float* __restrict__ C, int N, int doRelu) {
    const int M = N_NODES;
    __shared__ float As[TK][68];
    __shared__ float Ws[TK][68];
    int tid = threadIdx.x;
    int tx = tid & 15, ty = tid >> 4;
    int m0 = blockIdx.x * 64, n0 = blockIdx.y * 64;
    float acc[4][4] = {{0.f}};

    for (int pass = 0; pass < 2; ++pass) {
        const float* A = pass ? A2 : A1;
        const float* W = pass ? W2 : W1;
        int K = pass ? K2 : K1;
        if (K == 0) continue;
        for (int kc = 0; kc < K; kc += TK) {
            // stage A: 64 rows x 16 k (threads: 16 k-cols x 16 row-groups)
            {
                int kq = tid & 15, mb = tid >> 4;
#pragma unroll
                for (int ii = 0; ii < 4; ++ii) {
                    int m = mb + ii * 16;
                    int gm = m0 + m, gk = kc + kq;
                    As[kq][m] = (gm < M && gk < K) ? A[(size_t)gm * K + gk] : 0.f;
                }
            }
            // stage W: 16 k x 64 n (threads: 64 n x 4 k-groups)
            {
                int n = tid & 63, kb = tid >> 6;
#pragma unroll
                for (int ii = 0; ii < 4; ++ii) {
                    int k = kb * 4 + ii;
                    int gk = kc + k, gn = n0 + n;
                    Ws[k][n] = (gk < K && gn < N) ? W[(size_t)gk * N + gn] : 0.f;
                }
            }
            __syncthreads();
#pragma unroll
            for (int k = 0; k < TK; ++k) {
                float4 a = *(const float4*)&As[k][ty * 4];
                float4 w = *(const float4*)&Ws[k][tx * 4];
                float av[4] = {a.x, a.y, a.z, a.w};
                float wv[4] = {w.x, w.y, w.z, w.w};
#pragma unroll
                for (int i = 0; i < 4; ++i)
#pragma unroll
                    for (int j = 0; j < 4; ++j)
                        acc[i][j] += av[i] * wv[j];
            }
            __syncthreads();
        }
    }
    // epilogue
#pragma unroll
    for (int i = 0; i < 4; ++i) {
        int gm = m0 + ty * 4 + i;
        if (gm >= M) continue;
#pragma unroll
        for (int j = 0; j < 4; ++j) {
            int gn = n0 + tx * 4 + j;
            if (gn >= N) continue;
            float v = acc[i][j];
            if (bias)   v += bias[gn];
            if (addend) v += addend[(size_t)gm * N + gn];
            if (doRelu) v = fmaxf(v, 0.f);
            C[(size_t)gm * N + gn] = v;
        }
    }
}

// ------------------------------------------- layer 4 (self-GEMM) + pooling
// pool[g][j] += h3[v]@Ws4[:,j] + b4[j] + agg4[v][j]   (agg4 already invdeg-scaled)
__global__ void k_layer4(const float* __restrict__ h3, const float* __restrict__ agg4,
                         const float* __restrict__ Ws,
                         const float* __restrict__ b, const int* __restrict__ gid,
                         float* __restrict__ pool) {
    int wid = (blockIdx.x * blockDim.x + threadIdx.x) >> 6;
    int lane = threadIdx.x & 63;
    if (wid >= N_NODES) return;
    const float* hr = h3 + (size_t)wid * 103;
    float h0 = (lane < 103) ? hr[lane] : 0.f;
    float h1 = (lane + 64 < 103) ? hr[lane + 64] : 0.f;
    float p[5];
#pragma unroll
    for (int j = 0; j < 5; ++j) {
        float w0 = (lane < 103) ? Ws[lane * 5 + j] : 0.f;
        float w1 = (lane + 64 < 103) ? Ws[(lane + 64) * 5 + j] : 0.f;
        p[j] = h0 * w0 + h1 * w1;
    }
#pragma unroll
    for (int off = 32; off > 0; off >>= 1) {
#pragma unroll
        for (int j = 0; j < 5; ++j) p[j] += __shfl_down(p[j], off, 64);
    }
    if (lane == 0) {
        int g = gid[wid];
#pragma unroll
        for (int j = 0; j < 5; ++j) {
            float v = p[j] + b[j] + agg4[(size_t)wid * 5 + j];
            atomicAdd(&pool[g * 5 + j], v);
        }
    }
}

__global__ void k_finalize(const float* __restrict__ pool, const float* __restrict__ cntg,
                           float* __restrict__ out) {
    int i = threadIdx.x;
    if (i < N_GRAPHS * 5) {
        int g = i / 5;
        out[i] = pool[i] / fmaxf(cntg[g], 1.0f);
    }
}

// --------------------------------------------------------------- launcher
extern "C" void kernel_launch(void* const* d_in, const int* in_sizes, int n_in,
                              void* d_out, int out_size, void* d_ws, size_t ws_size,
                              hipStream_t stream) {
    const float* x   = (const float*)d_in[0];
    const int*   src = (const int*)d_in[1];
    const int*   dst = (const int*)d_in[2];
    const int*   gid = (const int*)d_in[3];
    const float* Ws1 = (const float*)d_in[4],  *Wn1 = (const float*)d_in[5],  *b1 = (const float*)d_in[6];
    const float* Ws2 = (const float*)d_in[7],  *Wn2 = (const float*)d_in[8],  *b2 = (const float*)d_in[9];
    const float* Ws3 = (const float*)d_in[10], *Wn3 = (const float*)d_in[11], *b3 = (const float*)d_in[12];
    const float* Ws4 = (const float*)d_in[13], *Wn4 = (const float*)d_in[14], *b4 = (const float*)d_in[15];
    float* out = (float*)d_out;

    char* ws = (char*)d_ws;
    size_t off = 0;
    auto alloc = [&](size_t bytes) -> void* {
        void* p = ws + off;
        off += (bytes + 255) & ~(size_t)255;
        return p;
    };
    float* bufA    = (float*)alloc((size_t)N_NODES * 128 * 4);
    float* bufB    = (float*)alloc((size_t)N_NODES * 128 * 4);
    float* bufC    = (float*)alloc((size_t)N_NODES * 128 * 4);
    int*   csr     = (int*)  alloc((size_t)N_EDGES * 4);
    int*   rs      = (int*)  alloc((size_t)(N_NODES + 1) * 4);
    int*   cursor  = (int*)  alloc((size_t)N_NODES * 4);
    int*   count   = (int*)  alloc((size_t)N_NODES * 4);
    int*   partials= (int*)  alloc(128 * 4);
    float* invdeg  = (float*)alloc((size_t)N_NODES * 4);
    float* cntg    = (float*)alloc(N_GRAPHS * 4);
    float* pool    = (float*)alloc(N_GRAPHS * 5 * 4);

    hipMemsetAsync(count, 0, (size_t)N_NODES * 4, stream);
    hipMemsetAsync(cntg, 0, N_GRAPHS * 4, stream);
    hipMemsetAsync(pool, 0, N_GRAPHS * 5 * 4, stream);

    const int SCAN_BLOCKS = (N_NODES + 1023) / 1024;  // 98
    k_count<<<(N_EDGES + 255) / 256, 256, 0, stream>>>(dst, count);
    k_scan1<<<SCAN_BLOCKS, 256, 0, stream>>>(count, rs, partials);
    k_scan2<<<1, 128, 0, stream>>>(partials, SCAN_BLOCKS);
    k_scan3<<<SCAN_BLOCKS, 256, 0, stream>>>(rs, cursor, partials);
    k_invdeg<<<(N_NODES + 255) / 256, 256, 0, stream>>>(count, gid, invdeg, cntg);
    k_fill<<<(N_EDGES + 255) / 256, 256, 0, stream>>>(src, dst, cursor, csr);

    const int GATHER_BLOCKS = (N_NODES * 64 + 255) / 256;  // wave per node
    dim3 g2((N_NODES + 63) / 64, 2);
    dim3 g1((N_NODES + 63) / 64, 1);

    // ---- layer 1: aggregate x (F=64) then dual GEMM -> h1 (bufB, 128)
    k_gather<<<GATHER_BLOCKS, 256, 0, stream>>>(x, bufA, csr, rs, invdeg, 64);
    k_gemm<<<g2, 256, 0, stream>>>(x, Ws1, 64, bufA, Wn1, 64, nullptr, b1, bufB, 128, 1);

    // ---- layer 2: project h1 (bufB) -> P2 (bufA, 118); gather -> bufC; self+addend -> h2 (bufA)
    k_gemm<<<g2, 256, 0, stream>>>(bufB, Wn2, 128, nullptr, nullptr, 0, nullptr, nullptr, bufA, 118, 0);
    k_gather<<<GATHER_BLOCKS, 256, 0, stream>>>(bufA, bufC, csr, rs, invdeg, 118);
    k_gemm<<<g2, 256, 0, stream>>>(bufB, Ws2, 128, nullptr, nullptr, 0, bufC, b2, bufA, 118, 1);

    // ---- layer 3: project h2 (bufA) -> P3 (bufB, 103); gather -> bufC; self+addend -> h3 (bufB)
    k_gemm<<<g2, 256, 0, stream>>>(bufA, Wn3, 118, nullptr, nullptr, 0, nullptr, nullptr, bufB, 103, 0);
    k_gather<<<GATHER_BLOCKS, 256, 0, stream>>>(bufB, bufC, csr, rs, invdeg, 103);
    k_gemm<<<g2, 256, 0, stream>>>(bufA, Ws3, 118, nullptr, nullptr, 0, bufC, b3, bufB, 103, 1);

    // ---- layer 4: project h3 (bufB) -> P4 (bufA, 5); gather5 -> bufC; fused self-dot + pooling
    k_gemm<<<g1, 256, 0, stream>>>(bufB, Wn4, 103, nullptr, nullptr, 0, nullptr, nullptr, bufA, 5, 0);
    k_gather5<<<(N_NODES + 255) / 256, 256, 0, stream>>>(bufA, bufC, csr, rs, invdeg);
    k_layer4<<<GATHER_BLOCKS, 256, 0, stream>>>(bufB, bufC, Ws4, b4, gid, pool);
    k_finalize<<<1, 320, 0, stream>>>(pool, cntg, out);
}

// Round 3
// 1691.904 us; speedup vs baseline: 2.3560x; 2.3560x over previous
//
#include <hip/hip_runtime.h>
#include <hip/hip_bf16.h>

#define N_NODES 100000
#define N_EDGES 1600000
#define N_GRAPHS 64

// ---------------------------------------------------------------- CSR build
__global__ void k_count(const int* __restrict__ dst, int* __restrict__ count) {
    int e = blockIdx.x * blockDim.x + threadIdx.x;
    if (e < N_EDGES) atomicAdd(&count[dst[e]], 1);
}

// block-local exclusive scan, 1024 elems/block (256 thr x 4)
__global__ void k_scan1(const int* __restrict__ cnt, int* __restrict__ rs, int* __restrict__ partials) {
    __shared__ int s[256];
    int b = blockIdx.x, t = threadIdx.x;
    int base = b * 1024 + t * 4;
    int v0 = 0, v1 = 0, v2 = 0, v3 = 0;
    if (base + 3 < N_NODES) {
        int4 q = *(const int4*)(cnt + base);
        v0 = q.x; v1 = q.y; v2 = q.z; v3 = q.w;
    } else {
        if (base     < N_NODES) v0 = cnt[base];
        if (base + 1 < N_NODES) v1 = cnt[base + 1];
        if (base + 2 < N_NODES) v2 = cnt[base + 2];
        if (base + 3 < N_NODES) v3 = cnt[base + 3];
    }
    int tsum = v0 + v1 + v2 + v3;
    s[t] = tsum; __syncthreads();
    for (int off = 1; off < 256; off <<= 1) {
        int x = (t >= off) ? s[t - off] : 0;
        __syncthreads();
        s[t] += x;
        __syncthreads();
    }
    int excl = s[t] - tsum;
    if (base     < N_NODES) rs[base]     = excl;
    excl += v0;
    if (base + 1 < N_NODES) rs[base + 1] = excl;
    excl += v1;
    if (base + 2 < N_NODES) rs[base + 2] = excl;
    excl += v2;
    if (base + 3 < N_NODES) rs[base + 3] = excl;
    if (t == 255) partials[b] = s[255];
}

__global__ void k_scan2(int* __restrict__ partials, int nb) {
    __shared__ int s[128];
    int t = threadIdx.x;
    int v = (t < nb) ? partials[t] : 0;
    s[t] = v; __syncthreads();
    for (int off = 1; off < 128; off <<= 1) {
        int x = (t >= off) ? s[t - off] : 0;
        __syncthreads();
        s[t] += x;
        __syncthreads();
    }
    if (t < nb) partials[t] = s[t] - v;  // exclusive
}

__global__ void k_scan3(int* __restrict__ rs, int* __restrict__ cursor, const int* __restrict__ partials) {
    int b = blockIdx.x, t = threadIdx.x;
    int off = partials[b];
    int base = b * 1024 + t * 4;
#pragma unroll
    for (int i = 0; i < 4; ++i) {
        int idx = base + i;
        if (idx < N_NODES) {
            int v = rs[idx] + off;
            rs[idx] = v;
            cursor[idx] = v;
        }
    }
    if (b == 0 && t == 0) rs[N_NODES] = N_EDGES;
}

__global__ void k_invdeg(const int* __restrict__ count, float* __restrict__ invdeg) {
    int v = blockIdx.x * blockDim.x + threadIdx.x;
    if (v >= N_NODES) return;
    int d = count[v];
    invdeg[v] = d > 0 ? 1.0f / (float)d : 0.0f;
}

// first index with gid >= g, for g in [0, N_GRAPHS]; gid is sorted
__global__ void k_gbounds(const int* __restrict__ gid, int* __restrict__ gstart) {
    int g = threadIdx.x;
    if (g > N_GRAPHS) return;
    int lo = 0, hi = N_NODES;
    while (lo < hi) {
        int mid = (lo + hi) >> 1;
        if (gid[mid] < g) lo = mid + 1; else hi = mid;
    }
    gstart[g] = lo;
}

__global__ void k_fill(const int* __restrict__ src, const int* __restrict__ dst,
                       int* __restrict__ cursor, int* __restrict__ csr) {
    int e = blockIdx.x * blockDim.x + threadIdx.x;
    if (e >= N_EDGES) return;
    int d = dst[e];
    int pos = atomicAdd(&cursor[d], 1);
    csr[pos] = src[e];
}

// ------------------------------------------------------- gather (wave/node)
// out[v][f] = invdeg[v] * sum_{e: dst=v} feat[src[e]][f],  F <= 128
__global__ void k_gather(const float* __restrict__ feat, float* __restrict__ out,
                         const int* __restrict__ csr, const int* __restrict__ rs,
                         const float* __restrict__ invdeg, int F) {
    int wid = (blockIdx.x * blockDim.x + threadIdx.x) >> 6;
    int lane = threadIdx.x & 63;
    if (wid >= N_NODES) return;
    int s0 = rs[wid], s1 = rs[wid + 1];
    int f1 = lane + 64;
    float acc0 = 0.f, acc1 = 0.f;
    for (int j = s0; j < s1; ++j) {
        int s = csr[j];
        const float* row = feat + (size_t)s * F;
        if (lane < F) acc0 += row[lane];
        if (f1 < F)   acc1 += row[f1];
    }
    float sc = invdeg[wid];
    float* orow = out + (size_t)wid * F;
    if (lane < F) orow[lane] = acc0 * sc;
    if (f1 < F)   orow[f1]   = acc1 * sc;
}

__global__ void k_gather5(const float* __restrict__ feat, float* __restrict__ out,
                          const int* __restrict__ csr, const int* __restrict__ rs,
                          const float* __restrict__ invdeg) {
    int v = blockIdx.x * blockDim.x + threadIdx.x;
    if (v >= N_NODES) return;
    int s0 = rs[v], s1 = rs[v + 1];
    float a0 = 0, a1 = 0, a2 = 0, a3 = 0, a4 = 0;
    for (int j = s0; j < s1; ++j) {
        const float* r = feat + (size_t)csr[j] * 5;
        a0 += r[0]; a1 += r[1]; a2 += r[2]; a3 += r[3]; a4 += r[4];
    }
    float sc = invdeg[v];
    float* o = out + (size_t)v * 5;
    o[0] = a0 * sc; o[1] = a1 * sc; o[2] = a2 * sc; o[3] = a3 * sc; o[4] = a4 * sc;
}

// ------------------------------------------------------------ fused fp32 GEMM
// C[M x N] = act( A1@W1 [+ A2@W2] [+ addend] [+ bias] )
// BM=64, BN=64, TK=16; 256 threads, each 4x4 outputs.
#define TK 16
__global__ __launch_bounds__(256) void k_gemm(
        const float* __restrict__ A1, const float* __restrict__ W1, int K1,
        const float* __restrict__ A2, const float* __restrict__ W2, int K2,
        const float* __restrict__ addend, const float* __restrict__ bias,
        float* __restrict__ C, int N, int doRelu) {
    const int M = N_NODES;
    __shared__ float As[TK][68];
    __shared__ float Ws[TK][68];
    int tid = threadIdx.x;
    int tx = tid & 15, ty = tid >> 4;
    int m0 = blockIdx.x * 64, n0 = blockIdx.y * 64;
    float acc[4][4] = {{0.f}};

    for (int pass = 0; pass < 2; ++pass) {
        const float* A = pass ? A2 : A1;
        const float* W = pass ? W2 : W1;
        int K = pass ? K2 : K1;
        if (K == 0) continue;
        for (int kc = 0; kc < K; kc += TK) {
            {
                int kq = tid & 15, mb = tid >> 4;
#pragma unroll
                for (int ii = 0; ii < 4; ++ii) {
                    int m = mb + ii * 16;
                    int gm = m0 + m, gk = kc + kq;
                    As[kq][m] = (gm < M && gk < K) ? A[(size_t)gm * K + gk] : 0.f;
                }
            }
            {
                int n = tid & 63, kb = tid >> 6;
#pragma unroll
                for (int ii = 0; ii < 4; ++ii) {
                    int k = kb * 4 + ii;
                    int gk = kc + k, gn = n0 + n;
                    Ws[k][n] = (gk < K && gn < N) ? W[(size_t)gk * N + gn] : 0.f;
                }
            }
            __syncthreads();
#pragma unroll
            for (int k = 0; k < TK; ++k) {
                float4 a = *(const float4*)&As[k][ty * 4];
                float4 w = *(const float4*)&Ws[k][tx * 4];
                float av[4] = {a.x, a.y, a.z, a.w};
                float wv[4] = {w.x, w.y, w.z, w.w};
#pragma unroll
                for (int i = 0; i < 4; ++i)
#pragma unroll
                    for (int j = 0; j < 4; ++j)
                        acc[i][j] += av[i] * wv[j];
            }
            __syncthreads();
        }
    }
#pragma unroll
    for (int i = 0; i < 4; ++i) {
        int gm = m0 + ty * 4 + i;
        if (gm >= M) continue;
#pragma unroll
        for (int j = 0; j < 4; ++j) {
            int gn = n0 + tx * 4 + j;
            if (gn >= N) continue;
            float v = acc[i][j];
            if (bias)   v += bias[gn];
            if (addend) v += addend[(size_t)gm * N + gn];
            if (doRelu) v = fmaxf(v, 0.f);
            C[(size_t)gm * N + gn] = v;
        }
    }
}

// ------------------------------------------------ chunked segment-sum pooling
// pool[g][f] += sum over nodes v in chunk with gid[v]==g of feat[v][f]
// graph_ids sorted -> each 256-node chunk spans ~1-2 graphs -> few atomics.
__global__ void k_pool(const float* __restrict__ feat, const int* __restrict__ gid,
                       float* __restrict__ pool, int F) {
    int base = blockIdx.x * 256;
    if (base >= N_NODES) return;
    int end = base + 256 < N_NODES ? base + 256 : N_NODES;
    int f = threadIdx.x;  // 128 threads
    float local = 0.f;
    int curg = gid[base];
    for (int v = base; v < end; ++v) {
        int g = gid[v];
        if (g != curg) {
            if (f < F) atomicAdd(&pool[curg * F + f], local);
            local = 0.f;
            curg = g;
        }
        if (f < F) local += feat[(size_t)v * F + f];
    }
    if (f < F) atomicAdd(&pool[curg * F + f], local);
}

// out[g][j] = (pooledH[g]@Ws4[:,j] + cnt_g*b4[j] + pooledA[g][j]) / max(cnt_g,1)
__global__ void k_final(const float* __restrict__ pooledH, const float* __restrict__ pooledA,
                        const float* __restrict__ Ws4, const float* __restrict__ b4,
                        const int* __restrict__ gstart, float* __restrict__ out) {
    int idx = threadIdx.x;
    if (idx >= N_GRAPHS * 5) return;
    int g = idx / 5, j = idx % 5;
    float cnt = (float)(gstart[g + 1] - gstart[g]);
    float s = 0.f;
    for (int k = 0; k < 103; ++k) s += pooledH[g * 103 + k] * Ws4[k * 5 + j];
    out[idx] = (s + cnt * b4[j] + pooledA[idx]) / fmaxf(cnt, 1.0f);
}

// --------------------------------------------------------------- launcher
extern "C" void kernel_launch(void* const* d_in, const int* in_sizes, int n_in,
                              void* d_out, int out_size, void* d_ws, size_t ws_size,
                              hipStream_t stream) {
    const float* x   = (const float*)d_in[0];
    const int*   src = (const int*)d_in[1];
    const int*   dst = (const int*)d_in[2];
    const int*   gid = (const int*)d_in[3];
    const float* Ws1 = (const float*)d_in[4],  *Wn1 = (const float*)d_in[5],  *b1 = (const float*)d_in[6];
    const float* Ws2 = (const float*)d_in[7],  *Wn2 = (const float*)d_in[8],  *b2 = (const float*)d_in[9];
    const float* Ws3 = (const float*)d_in[10], *Wn3 = (const float*)d_in[11], *b3 = (const float*)d_in[12];
    const float* Ws4 = (const float*)d_in[13], *Wn4 = (const float*)d_in[14], *b4 = (const float*)d_in[15];
    float* out = (float*)d_out;

    char* ws = (char*)d_ws;
    size_t off = 0;
    auto alloc = [&](size_t bytes) -> void* {
        void* p = ws + off;
        off += (bytes + 255) & ~(size_t)255;
        return p;
    };
    float* bufA    = (float*)alloc((size_t)N_NODES * 128 * 4);
    float* bufB    = (float*)alloc((size_t)N_NODES * 128 * 4);
    float* bufC    = (float*)alloc((size_t)N_NODES * 128 * 4);
    int*   csr     = (int*)  alloc((size_t)N_EDGES * 4);
    int*   rs      = (int*)  alloc((size_t)(N_NODES + 1) * 4);
    int*   cursor  = (int*)  alloc((size_t)N_NODES * 4);
    int*   count   = (int*)  alloc((size_t)N_NODES * 4);
    int*   partials= (int*)  alloc(128 * 4);
    float* invdeg  = (float*)alloc((size_t)N_NODES * 4);
    int*   gstart  = (int*)  alloc((N_GRAPHS + 1) * 4);
    float* pooledH = (float*)alloc(N_GRAPHS * 103 * 4);
    float* pooledA = (float*)alloc(N_GRAPHS * 5 * 4);

    hipMemsetAsync(count, 0, (size_t)N_NODES * 4, stream);
    hipMemsetAsync(pooledH, 0, N_GRAPHS * 103 * 4, stream);
    hipMemsetAsync(pooledA, 0, N_GRAPHS * 5 * 4, stream);

    const int SCAN_BLOCKS = (N_NODES + 1023) / 1024;  // 98
    k_count<<<(N_EDGES + 255) / 256, 256, 0, stream>>>(dst, count);
    k_scan1<<<SCAN_BLOCKS, 256, 0, stream>>>(count, rs, partials);
    k_scan2<<<1, 128, 0, stream>>>(partials, SCAN_BLOCKS);
    k_scan3<<<SCAN_BLOCKS, 256, 0, stream>>>(rs, cursor, partials);
    k_invdeg<<<(N_NODES + 255) / 256, 256, 0, stream>>>(count, invdeg);
    k_gbounds<<<1, 128, 0, stream>>>(gid, gstart);
    k_fill<<<(N_EDGES + 255) / 256, 256, 0, stream>>>(src, dst, cursor, csr);

    const int GATHER_BLOCKS = (N_NODES * 64 + 255) / 256;  // wave per node
    dim3 g2((N_NODES + 63) / 64, 2);
    dim3 g1((N_NODES + 63) / 64, 1);
    const int POOL_BLOCKS = (N_NODES + 255) / 256;  // 391

    // ---- layer 1: aggregate x (F=64) then dual GEMM -> h1 (bufB, 128)
    k_gather<<<GATHER_BLOCKS, 256, 0, stream>>>(x, bufA, csr, rs, invdeg, 64);
    k_gemm<<<g2, 256, 0, stream>>>(x, Ws1, 64, bufA, Wn1, 64, nullptr, b1, bufB, 128, 1);

    // ---- layer 2: project h1 (bufB) -> P2 (bufA, 118); gather -> bufC; self+addend -> h2 (bufA)
    k_gemm<<<g2, 256, 0, stream>>>(bufB, Wn2, 128, nullptr, nullptr, 0, nullptr, nullptr, bufA, 118, 0);
    k_gather<<<GATHER_BLOCKS, 256, 0, stream>>>(bufA, bufC, csr, rs, invdeg, 118);
    k_gemm<<<g2, 256, 0, stream>>>(bufB, Ws2, 128, nullptr, nullptr, 0, bufC, b2, bufA, 118, 1);

    // ---- layer 3: project h2 (bufA) -> P3 (bufB, 103); gather -> bufC; self+addend -> h3 (bufB)
    k_gemm<<<g2, 256, 0, stream>>>(bufA, Wn3, 118, nullptr, nullptr, 0, nullptr, nullptr, bufB, 103, 0);
    k_gather<<<GATHER_BLOCKS, 256, 0, stream>>>(bufB, bufC, csr, rs, invdeg, 103);
    k_gemm<<<g2, 256, 0, stream>>>(bufA, Ws3, 118, nullptr, nullptr, 0, bufC, b3, bufB, 103, 1);

    // ---- layer 4: project h3 (bufB) -> P4 (bufA, 5); gather5 -> agg4 (bufC)
    k_gemm<<<g1, 256, 0, stream>>>(bufB, Wn4, 103, nullptr, nullptr, 0, nullptr, nullptr, bufA, 5, 0);
    k_gather5<<<(N_NODES + 255) / 256, 256, 0, stream>>>(bufA, bufC, csr, rs, invdeg);

    // ---- pooling: segment-sum h3 and agg4, then finalize
    k_pool<<<POOL_BLOCKS, 128, 0, stream>>>(bufB, gid, pooledH, 103);
    k_pool<<<POOL_BLOCKS, 128, 0, stream>>>(bufC, gid, pooledA, 5);
    k_final<<<1, 320, 0, stream>>>(pooledH, pooledA, Ws4, b4, gstart, out);
}

// Round 4
// 1432.725 us; speedup vs baseline: 2.7822x; 1.1809x over previous
//
#include <hip/hip_runtime.h>
#include <hip/hip_bf16.h>

#define N_NODES 100000
#define N_EDGES 1600000
#define N_GRAPHS 64

// ---------------------------------------------------------------- CSR build
__global__ void k_count(const int* __restrict__ dst, int* __restrict__ count) {
    int e = blockIdx.x * blockDim.x + threadIdx.x;
    if (e < N_EDGES) atomicAdd(&count[dst[e]], 1);
}

// block-local exclusive scan, 1024 elems/block (256 thr x 4)
__global__ void k_scan1(const int* __restrict__ cnt, int* __restrict__ rs, int* __restrict__ partials) {
    __shared__ int s[256];
    int b = blockIdx.x, t = threadIdx.x;
    int base = b * 1024 + t * 4;
    int v0 = 0, v1 = 0, v2 = 0, v3 = 0;
    if (base + 3 < N_NODES) {
        int4 q = *(const int4*)(cnt + base);
        v0 = q.x; v1 = q.y; v2 = q.z; v3 = q.w;
    } else {
        if (base     < N_NODES) v0 = cnt[base];
        if (base + 1 < N_NODES) v1 = cnt[base + 1];
        if (base + 2 < N_NODES) v2 = cnt[base + 2];
        if (base + 3 < N_NODES) v3 = cnt[base + 3];
    }
    int tsum = v0 + v1 + v2 + v3;
    s[t] = tsum; __syncthreads();
    for (int off = 1; off < 256; off <<= 1) {
        int x = (t >= off) ? s[t - off] : 0;
        __syncthreads();
        s[t] += x;
        __syncthreads();
    }
    int excl = s[t] - tsum;
    if (base     < N_NODES) rs[base]     = excl;
    excl += v0;
    if (base + 1 < N_NODES) rs[base + 1] = excl;
    excl += v1;
    if (base + 2 < N_NODES) rs[base + 2] = excl;
    excl += v2;
    if (base + 3 < N_NODES) rs[base + 3] = excl;
    if (t == 255) partials[b] = s[255];
}

__global__ void k_scan2(int* __restrict__ partials, int nb) {
    __shared__ int s[128];
    int t = threadIdx.x;
    int v = (t < nb) ? partials[t] : 0;
    s[t] = v; __syncthreads();
    for (int off = 1; off < 128; off <<= 1) {
        int x = (t >= off) ? s[t - off] : 0;
        __syncthreads();
        s[t] += x;
        __syncthreads();
    }
    if (t < nb) partials[t] = s[t] - v;  // exclusive
}

__global__ void k_scan3(int* __restrict__ rs, int* __restrict__ cursor, const int* __restrict__ partials) {
    int b = blockIdx.x, t = threadIdx.x;
    int off = partials[b];
    int base = b * 1024 + t * 4;
#pragma unroll
    for (int i = 0; i < 4; ++i) {
        int idx = base + i;
        if (idx < N_NODES) {
            int v = rs[idx] + off;
            rs[idx] = v;
            cursor[idx] = v;
        }
    }
    if (b == 0 && t == 0) rs[N_NODES] = N_EDGES;
}

__global__ void k_invdeg(const int* __restrict__ count, float* __restrict__ invdeg) {
    int v = blockIdx.x * blockDim.x + threadIdx.x;
    if (v >= N_NODES) return;
    int d = count[v];
    invdeg[v] = d > 0 ? 1.0f / (float)d : 0.0f;
}

// first index with gid >= g, for g in [0, N_GRAPHS]; gid is sorted
__global__ void k_gbounds(const int* __restrict__ gid, int* __restrict__ gstart) {
    int g = threadIdx.x;
    if (g > N_GRAPHS) return;
    int lo = 0, hi = N_NODES;
    while (lo < hi) {
        int mid = (lo + hi) >> 1;
        if (gid[mid] < g) lo = mid + 1; else hi = mid;
    }
    gstart[g] = lo;
}

__global__ void k_fill(const int* __restrict__ src, const int* __restrict__ dst,
                       int* __restrict__ cursor, int* __restrict__ csr) {
    int e = blockIdx.x * blockDim.x + threadIdx.x;
    if (e >= N_EDGES) return;
    int d = dst[e];
    int pos = atomicAdd(&cursor[d], 1);
    csr[pos] = src[e];
}

// ------------------------------------------------------- gather (wave/node)
// out[v][f] = invdeg[v] * sum_{e: dst=v} feat[src[e]][f],  64 <= F <= 128
// Unrolled by 8: 16 outstanding row loads per wave to hide L3/HBM latency.
__global__ __launch_bounds__(256) void k_gather(
        const float* __restrict__ feat, float* __restrict__ out,
        const int* __restrict__ csr, const int* __restrict__ rs,
        const float* __restrict__ invdeg, int F) {
    int wid = (blockIdx.x * blockDim.x + threadIdx.x) >> 6;
    int lane = threadIdx.x & 63;
    if (wid >= N_NODES) return;
    int s0 = rs[wid], s1 = rs[wid + 1];
    int f1 = lane + 64;
    bool q1 = f1 < F;
    float acc0 = 0.f, acc1 = 0.f;
    int j = s0;
    for (; j + 8 <= s1; j += 8) {
        int idx[8];
#pragma unroll
        for (int u = 0; u < 8; ++u) idx[u] = csr[j + u];
        float a[8], b[8];
#pragma unroll
        for (int u = 0; u < 8; ++u) {
            const float* r = feat + (size_t)idx[u] * F;
            a[u] = r[lane];            // lane < 64 <= F always
            b[u] = q1 ? r[f1] : 0.f;
        }
#pragma unroll
        for (int u = 0; u < 8; ++u) { acc0 += a[u]; acc1 += b[u]; }
    }
    for (; j < s1; ++j) {
        const float* r = feat + (size_t)csr[j] * F;
        acc0 += r[lane];
        acc1 += q1 ? r[f1] : 0.f;
    }
    float sc = invdeg[wid];
    float* orow = out + (size_t)wid * F;
    orow[lane] = acc0 * sc;
    if (q1) orow[f1] = acc1 * sc;
}

// thread-per-node, F=5; unrolled by 4 (20 outstanding loads/thread)
__global__ __launch_bounds__(256) void k_gather5(
        const float* __restrict__ feat, float* __restrict__ out,
        const int* __restrict__ csr, const int* __restrict__ rs,
        const float* __restrict__ invdeg) {
    int v = blockIdx.x * blockDim.x + threadIdx.x;
    if (v >= N_NODES) return;
    int s0 = rs[v], s1 = rs[v + 1];
    float a[5] = {0.f, 0.f, 0.f, 0.f, 0.f};
    int j = s0;
    for (; j + 4 <= s1; j += 4) {
        int i0 = csr[j], i1 = csr[j + 1], i2 = csr[j + 2], i3 = csr[j + 3];
        const float* r0 = feat + (size_t)i0 * 5;
        const float* r1 = feat + (size_t)i1 * 5;
        const float* r2 = feat + (size_t)i2 * 5;
        const float* r3 = feat + (size_t)i3 * 5;
        float t0[5], t1[5], t2[5], t3[5];
#pragma unroll
        for (int c = 0; c < 5; ++c) { t0[c] = r0[c]; t1[c] = r1[c]; t2[c] = r2[c]; t3[c] = r3[c]; }
#pragma unroll
        for (int c = 0; c < 5; ++c) a[c] += (t0[c] + t1[c]) + (t2[c] + t3[c]);
    }
    for (; j < s1; ++j) {
        const float* r = feat + (size_t)csr[j] * 5;
#pragma unroll
        for (int c = 0; c < 5; ++c) a[c] += r[c];
    }
    float sc = invdeg[v];
    float* o = out + (size_t)v * 5;
#pragma unroll
    for (int c = 0; c < 5; ++c) o[c] = a[c] * sc;
}

// ------------------------------------------------------------ fused fp32 GEMM
// C[M x N] = act( A1@W1 [+ A2@W2] [+ addend] [+ bias] )
// BM=128, BN=64, TK=16; 256 threads, each 8x4 outputs.
#define TK 16
__global__ __launch_bounds__(256) void k_gemm(
        const float* __restrict__ A1, const float* __restrict__ W1, int K1,
        const float* __restrict__ A2, const float* __restrict__ W2, int K2,
        const float* __restrict__ addend, const float* __restrict__ bias,
        float* __restrict__ C, int N, int doRelu) {
    const int M = N_NODES;
    __shared__ float As[TK][132];
    __shared__ float Ws[TK][68];
    int tid = threadIdx.x;
    int tx = tid & 15, ty = tid >> 4;
    int m0 = blockIdx.x * 128, n0 = blockIdx.y * 64;
    float acc[8][4] = {{0.f}};

    for (int pass = 0; pass < 2; ++pass) {
        const float* A = pass ? A2 : A1;
        const float* W = pass ? W2 : W1;
        int K = pass ? K2 : K1;
        if (K == 0) continue;
        for (int kc = 0; kc < K; kc += TK) {
            // stage A: 128 rows x 16 k (thread (kq=tid&15, mb=tid>>4) does 8 rows)
            {
                int kq = tid & 15, mb = tid >> 4;
                int gk = kc + kq;
                bool kok = gk < K;
#pragma unroll
                for (int ii = 0; ii < 8; ++ii) {
                    int m = mb + ii * 16;
                    int gm = m0 + m;
                    As[kq][m] = (kok && gm < M) ? A[(size_t)gm * K + gk] : 0.f;
                }
            }
            // stage W: 16 k x 64 n
            {
                int n = tid & 63, kb = tid >> 6;
                int gn = n0 + n;
#pragma unroll
                for (int ii = 0; ii < 4; ++ii) {
                    int k = kb * 4 + ii;
                    int gk = kc + k;
                    Ws[k][n] = (gk < K && gn < N) ? W[(size_t)gk * N + gn] : 0.f;
                }
            }
            __syncthreads();
#pragma unroll
            for (int k = 0; k < TK; ++k) {
                float4 a0 = *(const float4*)&As[k][ty * 8];
                float4 a1 = *(const float4*)&As[k][ty * 8 + 4];
                float4 w  = *(const float4*)&Ws[k][tx * 4];
                float av[8] = {a0.x, a0.y, a0.z, a0.w, a1.x, a1.y, a1.z, a1.w};
                float wv[4] = {w.x, w.y, w.z, w.w};
#pragma unroll
                for (int i = 0; i < 8; ++i)
#pragma unroll
                    for (int jj = 0; jj < 4; ++jj)
                        acc[i][jj] += av[i] * wv[jj];
            }
            __syncthreads();
        }
    }
#pragma unroll
    for (int i = 0; i < 8; ++i) {
        int gm = m0 + ty * 8 + i;
        if (gm >= M) continue;
#pragma unroll
        for (int jj = 0; jj < 4; ++jj) {
            int gn = n0 + tx * 4 + jj;
            if (gn >= N) continue;
            float v = acc[i][jj];
            if (bias)   v += bias[gn];
            if (addend) v += addend[(size_t)gm * N + gn];
            if (doRelu) v = fmaxf(v, 0.f);
            C[(size_t)gm * N + gn] = v;
        }
    }
}

// ------------------------------------------------ chunked segment-sum pooling
__global__ void k_pool(const float* __restrict__ feat, const int* __restrict__ gid,
                       float* __restrict__ pool, int F) {
    int base = blockIdx.x * 256;
    if (base >= N_NODES) return;
    int end = base + 256 < N_NODES ? base + 256 : N_NODES;
    int f = threadIdx.x;  // 128 threads
    float local = 0.f;
    int curg = gid[base];
    for (int v = base; v < end; ++v) {
        int g = gid[v];
        if (g != curg) {
            if (f < F) atomicAdd(&pool[curg * F + f], local);
            local = 0.f;
            curg = g;
        }
        if (f < F) local += feat[(size_t)v * F + f];
    }
    if (f < F) atomicAdd(&pool[curg * F + f], local);
}

// out[g][j] = (pooledH[g]@Ws4[:,j] + cnt_g*b4[j] + pooledA[g][j]) / max(cnt_g,1)
__global__ void k_final(const float* __restrict__ pooledH, const float* __restrict__ pooledA,
                        const float* __restrict__ Ws4, const float* __restrict__ b4,
                        const int* __restrict__ gstart, float* __restrict__ out) {
    int idx = threadIdx.x;
    if (idx >= N_GRAPHS * 5) return;
    int g = idx / 5, j = idx % 5;
    float cnt = (float)(gstart[g + 1] - gstart[g]);
    float s = 0.f;
    for (int k = 0; k < 103; ++k) s += pooledH[g * 103 + k] * Ws4[k * 5 + j];
    out[idx] = (s + cnt * b4[j] + pooledA[idx]) / fmaxf(cnt, 1.0f);
}

// --------------------------------------------------------------- launcher
extern "C" void kernel_launch(void* const* d_in, const int* in_sizes, int n_in,
                              void* d_out, int out_size, void* d_ws, size_t ws_size,
                              hipStream_t stream) {
    const float* x   = (const float*)d_in[0];
    const int*   src = (const int*)d_in[1];
    const int*   dst = (const int*)d_in[2];
    const int*   gid = (const int*)d_in[3];
    const float* Ws1 = (const float*)d_in[4],  *Wn1 = (const float*)d_in[5],  *b1 = (const float*)d_in[6];
    const float* Ws2 = (const float*)d_in[7],  *Wn2 = (const float*)d_in[8],  *b2 = (const float*)d_in[9];
    const float* Ws3 = (const float*)d_in[10], *Wn3 = (const float*)d_in[11], *b3 = (const float*)d_in[12];
    const float* Ws4 = (const float*)d_in[13], *Wn4 = (const float*)d_in[14], *b4 = (const float*)d_in[15];
    float* out = (float*)d_out;

    char* ws = (char*)d_ws;
    size_t off = 0;
    auto alloc = [&](size_t bytes) -> void* {
        void* p = ws + off;
        off += (bytes + 255) & ~(size_t)255;
        return p;
    };
    float* bufA    = (float*)alloc((size_t)N_NODES * 128 * 4);
    float* bufB    = (float*)alloc((size_t)N_NODES * 128 * 4);
    float* bufC    = (float*)alloc((size_t)N_NODES * 128 * 4);
    int*   csr     = (int*)  alloc((size_t)N_EDGES * 4);
    int*   rs      = (int*)  alloc((size_t)(N_NODES + 1) * 4);
    int*   cursor  = (int*)  alloc((size_t)N_NODES * 4);
    int*   count   = (int*)  alloc((size_t)N_NODES * 4);
    int*   partials= (int*)  alloc(128 * 4);
    float* invdeg  = (float*)alloc((size_t)N_NODES * 4);
    int*   gstart  = (int*)  alloc((N_GRAPHS + 1) * 4);
    float* pooledH = (float*)alloc(N_GRAPHS * 103 * 4);
    float* pooledA = (float*)alloc(N_GRAPHS * 5 * 4);

    hipMemsetAsync(count, 0, (size_t)N_NODES * 4, stream);
    hipMemsetAsync(pooledH, 0, N_GRAPHS * 103 * 4, stream);
    hipMemsetAsync(pooledA, 0, N_GRAPHS * 5 * 4, stream);

    const int SCAN_BLOCKS = (N_NODES + 1023) / 1024;  // 98
    k_count<<<(N_EDGES + 255) / 256, 256, 0, stream>>>(dst, count);
    k_scan1<<<SCAN_BLOCKS, 256, 0, stream>>>(count, rs, partials);
    k_scan2<<<1, 128, 0, stream>>>(partials, SCAN_BLOCKS);
    k_scan3<<<SCAN_BLOCKS, 256, 0, stream>>>(rs, cursor, partials);
    k_invdeg<<<(N_NODES + 255) / 256, 256, 0, stream>>>(count, invdeg);
    k_gbounds<<<1, 128, 0, stream>>>(gid, gstart);
    k_fill<<<(N_EDGES + 255) / 256, 256, 0, stream>>>(src, dst, cursor, csr);

    const int GATHER_BLOCKS = (N_NODES * 64 + 255) / 256;  // wave per node
    dim3 g2((N_NODES + 127) / 128, 2);
    dim3 g1((N_NODES + 127) / 128, 1);
    const int POOL_BLOCKS = (N_NODES + 255) / 256;  // 391

    // ---- layer 1: aggregate x (F=64) then dual GEMM -> h1 (bufB, 128)
    k_gather<<<GATHER_BLOCKS, 256, 0, stream>>>(x, bufA, csr, rs, invdeg, 64);
    k_gemm<<<g2, 256, 0, stream>>>(x, Ws1, 64, bufA, Wn1, 64, nullptr, b1, bufB, 128, 1);

    // ---- layer 2: project h1 (bufB) -> P2 (bufA, 118); gather -> bufC; self+addend -> h2 (bufA)
    k_gemm<<<g2, 256, 0, stream>>>(bufB, Wn2, 128, nullptr, nullptr, 0, nullptr, nullptr, bufA, 118, 0);
    k_gather<<<GATHER_BLOCKS, 256, 0, stream>>>(bufA, bufC, csr, rs, invdeg, 118);
    k_gemm<<<g2, 256, 0, stream>>>(bufB, Ws2, 128, nullptr, nullptr, 0, bufC, b2, bufA, 118, 1);

    // ---- layer 3: project h2 (bufA) -> P3 (bufB, 103); gather -> bufC; self+addend -> h3 (bufB)
    k_gemm<<<g2, 256, 0, stream>>>(bufA, Wn3, 118, nullptr, nullptr, 0, nullptr, nullptr, bufB, 103, 0);
    k_gather<<<GATHER_BLOCKS, 256, 0, stream>>>(bufB, bufC, csr, rs, invdeg, 103);
    k_gemm<<<g2, 256, 0, stream>>>(bufA, Ws3, 118, nullptr, nullptr, 0, bufC, b3, bufB, 103, 1);

    // ---- layer 4: project h3 (bufB) -> P4 (bufA, 5); gather5 -> agg4 (bufC)
    k_gemm<<<g1, 256, 0, stream>>>(bufB, Wn4, 103, nullptr, nullptr, 0, nullptr, nullptr, bufA, 5, 0);
    k_gather5<<<(N_NODES + 255) / 256, 256, 0, stream>>>(bufA, bufC, csr, rs, invdeg);

    // ---- pooling: segment-sum h3 and agg4, then finalize
    k_pool<<<POOL_BLOCKS, 128, 0, stream>>>(bufB, gid, pooledH, 103);
    k_pool<<<POOL_BLOCKS, 128, 0, stream>>>(bufC, gid, pooledA, 5);
    k_final<<<1, 320, 0, stream>>>(pooledH, pooledA, Ws4, b4, gstart, out);
}

// Round 5
// 1235.316 us; speedup vs baseline: 3.2268x; 1.1598x over previous
//
#include <hip/hip_runtime.h>
#include <hip/hip_bf16.h>

#define N_NODES 100000
#define N_EDGES 1600000
#define N_GRAPHS 64

typedef __attribute__((ext_vector_type(8))) short bf16x8;  // 8 bf16 = 4 VGPR
typedef __attribute__((ext_vector_type(4))) float f32x4;   // MFMA C/D frag

__device__ __forceinline__ ushort f2bf(float f) {
    return __builtin_bit_cast(ushort, __float2bfloat16(f));
}
__device__ __forceinline__ float bf2f(ushort u) {
    return __bfloat162float(__builtin_bit_cast(__hip_bfloat16, u));
}

// ---------------------------------------------------------------- CSR build
__global__ void k_count(const int* __restrict__ dst, int* __restrict__ count) {
    int e = blockIdx.x * blockDim.x + threadIdx.x;
    if (e < N_EDGES) atomicAdd(&count[dst[e]], 1);
}

__global__ void k_scan1(const int* __restrict__ cnt, int* __restrict__ rs, int* __restrict__ partials) {
    __shared__ int s[256];
    int b = blockIdx.x, t = threadIdx.x;
    int base = b * 1024 + t * 4;
    int v0 = 0, v1 = 0, v2 = 0, v3 = 0;
    if (base + 3 < N_NODES) {
        int4 q = *(const int4*)(cnt + base);
        v0 = q.x; v1 = q.y; v2 = q.z; v3 = q.w;
    } else {
        if (base     < N_NODES) v0 = cnt[base];
        if (base + 1 < N_NODES) v1 = cnt[base + 1];
        if (base + 2 < N_NODES) v2 = cnt[base + 2];
        if (base + 3 < N_NODES) v3 = cnt[base + 3];
    }
    int tsum = v0 + v1 + v2 + v3;
    s[t] = tsum; __syncthreads();
    for (int off = 1; off < 256; off <<= 1) {
        int x = (t >= off) ? s[t - off] : 0;
        __syncthreads();
        s[t] += x;
        __syncthreads();
    }
    int excl = s[t] - tsum;
    if (base     < N_NODES) rs[base]     = excl;
    excl += v0;
    if (base + 1 < N_NODES) rs[base + 1] = excl;
    excl += v1;
    if (base + 2 < N_NODES) rs[base + 2] = excl;
    excl += v2;
    if (base + 3 < N_NODES) rs[base + 3] = excl;
    if (t == 255) partials[b] = s[255];
}

__global__ void k_scan2(int* __restrict__ partials, int nb) {
    __shared__ int s[128];
    int t = threadIdx.x;
    int v = (t < nb) ? partials[t] : 0;
    s[t] = v; __syncthreads();
    for (int off = 1; off < 128; off <<= 1) {
        int x = (t >= off) ? s[t - off] : 0;
        __syncthreads();
        s[t] += x;
        __syncthreads();
    }
    if (t < nb) partials[t] = s[t] - v;  // exclusive
}

__global__ void k_scan3(int* __restrict__ rs, int* __restrict__ cursor, const int* __restrict__ partials) {
    int b = blockIdx.x, t = threadIdx.x;
    int off = partials[b];
    int base = b * 1024 + t * 4;
#pragma unroll
    for (int i = 0; i < 4; ++i) {
        int idx = base + i;
        if (idx < N_NODES) {
            int v = rs[idx] + off;
            rs[idx] = v;
            cursor[idx] = v;
        }
    }
    if (b == 0 && t == 0) rs[N_NODES] = N_EDGES;
}

__global__ void k_invdeg(const int* __restrict__ count, float* __restrict__ invdeg) {
    int v = blockIdx.x * blockDim.x + threadIdx.x;
    if (v >= N_NODES) return;
    int d = count[v];
    invdeg[v] = d > 0 ? 1.0f / (float)d : 0.0f;
}

__global__ void k_gbounds(const int* __restrict__ gid, int* __restrict__ gstart) {
    int g = threadIdx.x;
    if (g > N_GRAPHS) return;
    int lo = 0, hi = N_NODES;
    while (lo < hi) {
        int mid = (lo + hi) >> 1;
        if (gid[mid] < g) lo = mid + 1; else hi = mid;
    }
    gstart[g] = lo;
}

__global__ void k_fill(const int* __restrict__ src, const int* __restrict__ dst,
                       int* __restrict__ cursor, int* __restrict__ csr) {
    int e = blockIdx.x * blockDim.x + threadIdx.x;
    if (e >= N_EDGES) return;
    int d = dst[e];
    int pos = atomicAdd(&cursor[d], 1);
    csr[pos] = src[e];
}

// ------------------------------------------------------- gather (wave/node)
// out[v][f] = invdeg[v] * sum_{e: dst=v} feat[src[e]][f],  64 <= F <= 128
__global__ __launch_bounds__(256) void k_gather(
        const float* __restrict__ feat, float* __restrict__ out,
        const int* __restrict__ csr, const int* __restrict__ rs,
        const float* __restrict__ invdeg, int F) {
    int wid = (blockIdx.x * blockDim.x + threadIdx.x) >> 6;
    int lane = threadIdx.x & 63;
    if (wid >= N_NODES) return;
    int s0 = rs[wid], s1 = rs[wid + 1];
    int f1 = lane + 64;
    bool q1 = f1 < F;
    float acc0 = 0.f, acc1 = 0.f;
    int j = s0;
    for (; j + 8 <= s1; j += 8) {
        int idx[8];
#pragma unroll
        for (int u = 0; u < 8; ++u) idx[u] = csr[j + u];
        float a[8], b[8];
#pragma unroll
        for (int u = 0; u < 8; ++u) {
            const float* r = feat + (size_t)idx[u] * F;
            a[u] = r[lane];
            b[u] = q1 ? r[f1] : 0.f;
        }
#pragma unroll
        for (int u = 0; u < 8; ++u) { acc0 += a[u]; acc1 += b[u]; }
    }
    for (; j < s1; ++j) {
        const float* r = feat + (size_t)csr[j] * F;
        acc0 += r[lane];
        acc1 += q1 ? r[f1] : 0.f;
    }
    float sc = invdeg[wid];
    float* orow = out + (size_t)wid * F;
    orow[lane] = acc0 * sc;
    if (q1) orow[f1] = acc1 * sc;
}

// thread-per-node, F=5; unrolled by 4
__global__ __launch_bounds__(256) void k_gather5(
        const float* __restrict__ feat, float* __restrict__ out,
        const int* __restrict__ csr, const int* __restrict__ rs,
        const float* __restrict__ invdeg) {
    int v = blockIdx.x * blockDim.x + threadIdx.x;
    if (v >= N_NODES) return;
    int s0 = rs[v], s1 = rs[v + 1];
    float a[5] = {0.f, 0.f, 0.f, 0.f, 0.f};
    int j = s0;
    for (; j + 4 <= s1; j += 4) {
        int i0 = csr[j], i1 = csr[j + 1], i2 = csr[j + 2], i3 = csr[j + 3];
        const float* r0 = feat + (size_t)i0 * 5;
        const float* r1 = feat + (size_t)i1 * 5;
        const float* r2 = feat + (size_t)i2 * 5;
        const float* r3 = feat + (size_t)i3 * 5;
        float t0[5], t1[5], t2[5], t3[5];
#pragma unroll
        for (int c = 0; c < 5; ++c) { t0[c] = r0[c]; t1[c] = r1[c]; t2[c] = r2[c]; t3[c] = r3[c]; }
#pragma unroll
        for (int c = 0; c < 5; ++c) a[c] += (t0[c] + t1[c]) + (t2[c] + t3[c]);
    }
    for (; j < s1; ++j) {
        const float* r = feat + (size_t)csr[j] * 5;
#pragma unroll
        for (int c = 0; c < 5; ++c) a[c] += r[c];
    }
    float sc = invdeg[v];
    float* o = out + (size_t)v * 5;
#pragma unroll
    for (int c = 0; c < 5; ++c) o[c] = a[c] * sc;
}

// ------------------------------------------------------------ MFMA GEMM
// C[M x N] = act( A1@W1 [+ A2@W2] [+ addend] [+ bias] ), fp32 in/out.
// A converted to bf16 on the fly; W split into bf16 hi+lo (2 MFMA passes)
// to kill the coherent quantization error. fp32 accumulate.
// BM=128 (4 waves x 32 rows), BN=64, K-step 32. mfma_f32_16x16x32_bf16.
// Frag maps: A m=lane&15, k=(lane>>4)*8+j ; B n=lane&15, same k ;
// D col=lane&15, row=(lane>>4)*4+r  [m89-verified]. Any consistent k-perm
// misassumption cancels between A and B.
__global__ __launch_bounds__(256) void k_mgemm(
        const float* __restrict__ A1, const float* __restrict__ W1, int K1,
        const float* __restrict__ A2, const float* __restrict__ W2, int K2,
        const float* __restrict__ addend, const float* __restrict__ bias,
        float* __restrict__ C, int N, int doRelu) {
    const int M = N_NODES;
    __shared__ ushort As[128][40];   // [row][k], +8 pad (80B stride -> conflict-free-ish)
    __shared__ ushort Bhi[64][40];   // [n][k] (W transposed)
    __shared__ ushort Blo[64][40];
    int tid = threadIdx.x;
    int m0 = blockIdx.x * 128, n0 = blockIdx.y * 64;
    int wv = tid >> 6, lane = tid & 63;
    int lr = lane & 15, lg = lane >> 4;

    f32x4 acc[2][4];
#pragma unroll
    for (int i = 0; i < 2; ++i)
#pragma unroll
        for (int jn = 0; jn < 4; ++jn) acc[i][jn] = (f32x4){0.f, 0.f, 0.f, 0.f};

    for (int pass = 0; pass < 2; ++pass) {
        const float* A = pass ? A2 : A1;
        const float* W = pass ? W2 : W1;
        int K = pass ? K2 : K1;
        if (K == 0) continue;
        for (int kc = 0; kc < K; kc += 32) {
            // ---- stage A tile: 128 rows x 32 k, fp32 -> bf16
            {
                int arow = tid >> 4;            // 0..15
                int k2 = (tid & 15) * 2;        // even k
#pragma unroll
                for (int p = 0; p < 8; ++p) {
                    int row = p * 16 + arow;
                    int gm = m0 + row;
                    int gk = kc + k2;
                    float f0 = 0.f, f1 = 0.f;
                    if (gm < M) {
                        const float* ar = A + (size_t)gm * K;
                        if (gk < K)     f0 = ar[gk];
                        if (gk + 1 < K) f1 = ar[gk + 1];
                    }
                    *(uint*)&As[row][k2] = ((uint)f2bf(f1) << 16) | (uint)f2bf(f0);
                }
            }
            // ---- stage W tile transposed: 64 n x 32 k, hi/lo split
            {
                int n = tid & 63, kk0 = (tid >> 6) * 8;
                int gn = n0 + n;
#pragma unroll
                for (int i = 0; i < 8; i += 2) {
                    int gk = kc + kk0 + i;
                    float w0 = (gn < N && gk     < K) ? W[(size_t)(gk)     * N + gn] : 0.f;
                    float w1 = (gn < N && gk + 1 < K) ? W[(size_t)(gk + 1) * N + gn] : 0.f;
                    ushort h0 = f2bf(w0), h1 = f2bf(w1);
                    ushort l0 = f2bf(w0 - bf2f(h0)), l1 = f2bf(w1 - bf2f(h1));
                    *(uint*)&Bhi[n][kk0 + i] = ((uint)h1 << 16) | (uint)h0;
                    *(uint*)&Blo[n][kk0 + i] = ((uint)l1 << 16) | (uint)l0;
                }
            }
            __syncthreads();
            // ---- fragments + MFMA
            bf16x8 af0 = *(const bf16x8*)&As[wv * 32 + lr][lg * 8];
            bf16x8 af1 = *(const bf16x8*)&As[wv * 32 + 16 + lr][lg * 8];
#pragma unroll
            for (int nf = 0; nf < 4; ++nf) {
                bf16x8 bh = *(const bf16x8*)&Bhi[nf * 16 + lr][lg * 8];
                bf16x8 bl = *(const bf16x8*)&Blo[nf * 16 + lr][lg * 8];
                acc[0][nf] = __builtin_amdgcn_mfma_f32_16x16x32_bf16(af0, bh, acc[0][nf], 0, 0, 0);
                acc[1][nf] = __builtin_amdgcn_mfma_f32_16x16x32_bf16(af1, bh, acc[1][nf], 0, 0, 0);
                acc[0][nf] = __builtin_amdgcn_mfma_f32_16x16x32_bf16(af0, bl, acc[0][nf], 0, 0, 0);
                acc[1][nf] = __builtin_amdgcn_mfma_f32_16x16x32_bf16(af1, bl, acc[1][nf], 0, 0, 0);
            }
            __syncthreads();
        }
    }
    // ---- epilogue: D row=(lg*4+r), col=lr within each 16x16 frag
#pragma unroll
    for (int mi = 0; mi < 2; ++mi) {
#pragma unroll
        for (int nf = 0; nf < 4; ++nf) {
#pragma unroll
            for (int r = 0; r < 4; ++r) {
                int gm = m0 + wv * 32 + mi * 16 + lg * 4 + r;
                int gn = n0 + nf * 16 + lr;
                if (gm < M && gn < N) {
                    float v = acc[mi][nf][r];
                    if (bias)   v += bias[gn];
                    if (addend) v += addend[(size_t)gm * N + gn];
                    if (doRelu) v = fmaxf(v, 0.f);
                    C[(size_t)gm * N + gn] = v;
                }
            }
        }
    }
}

// ------------------------------------------------ chunked segment-sum pooling
__global__ void k_pool(const float* __restrict__ feat, const int* __restrict__ gid,
                       float* __restrict__ pool, int F) {
    int base = blockIdx.x * 256;
    if (base >= N_NODES) return;
    int end = base + 256 < N_NODES ? base + 256 : N_NODES;
    int f = threadIdx.x;  // 128 threads
    float local = 0.f;
    int curg = gid[base];
    for (int v = base; v < end; ++v) {
        int g = gid[v];
        if (g != curg) {
            if (f < F) atomicAdd(&pool[curg * F + f], local);
            local = 0.f;
            curg = g;
        }
        if (f < F) local += feat[(size_t)v * F + f];
    }
    if (f < F) atomicAdd(&pool[curg * F + f], local);
}

// out[g][j] = (pooledH[g]@Ws4[:,j] + cnt_g*b4[j] + pooledA[g][j]) / max(cnt_g,1)
__global__ void k_final(const float* __restrict__ pooledH, const float* __restrict__ pooledA,
                        const float* __restrict__ Ws4, const float* __restrict__ b4,
                        const int* __restrict__ gstart, float* __restrict__ out) {
    int idx = threadIdx.x;
    if (idx >= N_GRAPHS * 5) return;
    int g = idx / 5, j = idx % 5;
    float cnt = (float)(gstart[g + 1] - gstart[g]);
    float s = 0.f;
    for (int k = 0; k < 103; ++k) s += pooledH[g * 103 + k] * Ws4[k * 5 + j];
    out[idx] = (s + cnt * b4[j] + pooledA[idx]) / fmaxf(cnt, 1.0f);
}

// --------------------------------------------------------------- launcher
extern "C" void kernel_launch(void* const* d_in, const int* in_sizes, int n_in,
                              void* d_out, int out_size, void* d_ws, size_t ws_size,
                              hipStream_t stream) {
    const float* x   = (const float*)d_in[0];
    const int*   src = (const int*)d_in[1];
    const int*   dst = (const int*)d_in[2];
    const int*   gid = (const int*)d_in[3];
    const float* Ws1 = (const float*)d_in[4],  *Wn1 = (const float*)d_in[5],  *b1 = (const float*)d_in[6];
    const float* Ws2 = (const float*)d_in[7],  *Wn2 = (const float*)d_in[8],  *b2 = (const float*)d_in[9];
    const float* Ws3 = (const float*)d_in[10], *Wn3 = (const float*)d_in[11], *b3 = (const float*)d_in[12];
    const float* Ws4 = (const float*)d_in[13], *Wn4 = (const float*)d_in[14], *b4 = (const float*)d_in[15];
    float* out = (float*)d_out;

    char* ws = (char*)d_ws;
    size_t off = 0;
    auto alloc = [&](size_t bytes) -> void* {
        void* p = ws + off;
        off += (bytes + 255) & ~(size_t)255;
        return p;
    };
    float* bufA    = (float*)alloc((size_t)N_NODES * 128 * 4);
    float* bufB    = (float*)alloc((size_t)N_NODES * 128 * 4);
    float* bufC    = (float*)alloc((size_t)N_NODES * 128 * 4);
    int*   csr     = (int*)  alloc((size_t)N_EDGES * 4);
    int*   rs      = (int*)  alloc((size_t)(N_NODES + 1) * 4);
    int*   cursor  = (int*)  alloc((size_t)N_NODES * 4);
    int*   count   = (int*)  alloc((size_t)N_NODES * 4);
    int*   partials= (int*)  alloc(128 * 4);
    float* invdeg  = (float*)alloc((size_t)N_NODES * 4);
    int*   gstart  = (int*)  alloc((N_GRAPHS + 1) * 4);
    float* pooledH = (float*)alloc(N_GRAPHS * 103 * 4);
    float* pooledA = (float*)alloc(N_GRAPHS * 5 * 4);

    hipMemsetAsync(count, 0, (size_t)N_NODES * 4, stream);
    hipMemsetAsync(pooledH, 0, N_GRAPHS * 103 * 4, stream);
    hipMemsetAsync(pooledA, 0, N_GRAPHS * 5 * 4, stream);

    const int SCAN_BLOCKS = (N_NODES + 1023) / 1024;  // 98
    k_count<<<(N_EDGES + 255) / 256, 256, 0, stream>>>(dst, count);
    k_scan1<<<SCAN_BLOCKS, 256, 0, stream>>>(count, rs, partials);
    k_scan2<<<1, 128, 0, stream>>>(partials, SCAN_BLOCKS);
    k_scan3<<<SCAN_BLOCKS, 256, 0, stream>>>(rs, cursor, partials);
    k_invdeg<<<(N_NODES + 255) / 256, 256, 0, stream>>>(count, invdeg);
    k_gbounds<<<1, 128, 0, stream>>>(gid, gstart);
    k_fill<<<(N_EDGES + 255) / 256, 256, 0, stream>>>(src, dst, cursor, csr);

    const int GATHER_BLOCKS = (N_NODES * 64 + 255) / 256;  // wave per node
    dim3 g2((N_NODES + 127) / 128, 2);
    dim3 g1((N_NODES + 127) / 128, 1);
    const int POOL_BLOCKS = (N_NODES + 255) / 256;  // 391

    // ---- layer 1: aggregate x (F=64) then dual GEMM -> h1 (bufB, 128)
    k_gather<<<GATHER_BLOCKS, 256, 0, stream>>>(x, bufA, csr, rs, invdeg, 64);
    k_mgemm<<<g2, 256, 0, stream>>>(x, Ws1, 64, bufA, Wn1, 64, nullptr, b1, bufB, 128, 1);

    // ---- layer 2: project h1 (bufB) -> P2 (bufA, 118); gather -> bufC; self+addend -> h2 (bufA)
    k_mgemm<<<g2, 256, 0, stream>>>(bufB, Wn2, 128, nullptr, nullptr, 0, nullptr, nullptr, bufA, 118, 0);
    k_gather<<<GATHER_BLOCKS, 256, 0, stream>>>(bufA, bufC, csr, rs, invdeg, 118);
    k_mgemm<<<g2, 256, 0, stream>>>(bufB, Ws2, 128, nullptr, nullptr, 0, bufC, b2, bufA, 118, 1);

    // ---- layer 3: project h2 (bufA) -> P3 (bufB, 103); gather -> bufC; self+addend -> h3 (bufB)
    k_mgemm<<<g2, 256, 0, stream>>>(bufA, Wn3, 118, nullptr, nullptr, 0, nullptr, nullptr, bufB, 103, 0);
    k_gather<<<GATHER_BLOCKS, 256, 0, stream>>>(bufB, bufC, csr, rs, invdeg, 103);
    k_mgemm<<<g2, 256, 0, stream>>>(bufA, Ws3, 118, nullptr, nullptr, 0, bufC, b3, bufB, 103, 1);

    // ---- layer 4: project h3 (bufB) -> P4 (bufA, 5); gather5 -> agg4 (bufC)
    k_mgemm<<<g1, 256, 0, stream>>>(bufB, Wn4, 103, nullptr, nullptr, 0, nullptr, nullptr, bufA, 5, 0);
    k_gather5<<<(N_NODES + 255) / 256, 256, 0, stream>>>(bufA, bufC, csr, rs, invdeg);

    // ---- pooling: segment-sum h3 and agg4, then finalize
    k_pool<<<POOL_BLOCKS, 128, 0, stream>>>(bufB, gid, pooledH, 103);
    k_pool<<<POOL_BLOCKS, 128, 0, stream>>>(bufC, gid, pooledA, 5);
    k_final<<<1, 320, 0, stream>>>(pooledH, pooledA, Ws4, b4, gstart, out);
}

// Round 11
// 1028.126 us; speedup vs baseline: 3.8771x; 1.2015x over previous
//
#include <hip/hip_runtime.h>
#include <hip/hip_bf16.h>

#define N_NODES 100000
#define N_EDGES 1600000
#define N_GRAPHS 64

typedef __attribute__((ext_vector_type(8))) short bf16x8;  // 8 bf16 = 4 VGPR
typedef __attribute__((ext_vector_type(4))) float f32x4;   // MFMA C/D frag

__device__ __forceinline__ ushort f2bf(float f) {
    return __builtin_bit_cast(ushort, __float2bfloat16(f));
}
__device__ __forceinline__ float bf2f(ushort u) {
    return __builtin_bit_cast(float, (uint)u << 16);
}
__device__ __forceinline__ float bflo(uint d) { return __builtin_bit_cast(float, d << 16); }
__device__ __forceinline__ float bfhi(uint d) { return __builtin_bit_cast(float, d & 0xffff0000u); }
__device__ __forceinline__ uint packbf(float lo, float hi) {
    return ((uint)f2bf(hi) << 16) | (uint)f2bf(lo);
}

// ---------------------------------------------------------------- CSR build
__global__ void k_count(const int* __restrict__ dst, int* __restrict__ count) {
    int e = blockIdx.x * blockDim.x + threadIdx.x;
    if (e < N_EDGES) atomicAdd(&count[dst[e]], 1);
}

__global__ void k_scan1(const int* __restrict__ cnt, int* __restrict__ rs, int* __restrict__ partials) {
    __shared__ int s[256];
    int b = blockIdx.x, t = threadIdx.x;
    int base = b * 1024 + t * 4;
    int v0 = 0, v1 = 0, v2 = 0, v3 = 0;
    if (base + 3 < N_NODES) {
        int4 q = *(const int4*)(cnt + base);
        v0 = q.x; v1 = q.y; v2 = q.z; v3 = q.w;
    } else {
        if (base     < N_NODES) v0 = cnt[base];
        if (base + 1 < N_NODES) v1 = cnt[base + 1];
        if (base + 2 < N_NODES) v2 = cnt[base + 2];
        if (base + 3 < N_NODES) v3 = cnt[base + 3];
    }
    int tsum = v0 + v1 + v2 + v3;
    s[t] = tsum; __syncthreads();
    for (int off = 1; off < 256; off <<= 1) {
        int x = (t >= off) ? s[t - off] : 0;
        __syncthreads();
        s[t] += x;
        __syncthreads();
    }
    int excl = s[t] - tsum;
    if (base     < N_NODES) rs[base]     = excl;
    excl += v0;
    if (base + 1 < N_NODES) rs[base + 1] = excl;
    excl += v1;
    if (base + 2 < N_NODES) rs[base + 2] = excl;
    excl += v2;
    if (base + 3 < N_NODES) rs[base + 3] = excl;
    if (t == 255) partials[b] = s[255];
}

__global__ void k_scan2(int* __restrict__ partials, int nb) {
    __shared__ int s[128];
    int t = threadIdx.x;
    int v = (t < nb) ? partials[t] : 0;
    s[t] = v; __syncthreads();
    for (int off = 1; off < 128; off <<= 1) {
        int x = (t >= off) ? s[t - off] : 0;
        __syncthreads();
        s[t] += x;
        __syncthreads();
    }
    if (t < nb) partials[t] = s[t] - v;  // exclusive
}

__global__ void k_scan3(int* __restrict__ rs, int* __restrict__ cursor, const int* __restrict__ partials) {
    int b = blockIdx.x, t = threadIdx.x;
    int off = partials[b];
    int base = b * 1024 + t * 4;
#pragma unroll
    for (int i = 0; i < 4; ++i) {
        int idx = base + i;
        if (idx < N_NODES) {
            int v = rs[idx] + off;
            rs[idx] = v;
            cursor[idx] = v;
        }
    }
    if (b == 0 && t == 0) rs[N_NODES] = N_EDGES;
}

__global__ void k_invdeg(const int* __restrict__ count, float* __restrict__ invdeg) {
    int v = blockIdx.x * blockDim.x + threadIdx.x;
    if (v >= N_NODES) return;
    int d = count[v];
    invdeg[v] = d > 0 ? 1.0f / (float)d : 0.0f;
}

__global__ void k_gbounds(const int* __restrict__ gid, int* __restrict__ gstart) {
    int g = threadIdx.x;
    if (g > N_GRAPHS) return;
    int lo = 0, hi = N_NODES;
    while (lo < hi) {
        int mid = (lo + hi) >> 1;
        if (gid[mid] < g) lo = mid + 1; else hi = mid;
    }
    gstart[g] = lo;
}

__global__ void k_fill(const int* __restrict__ src, const int* __restrict__ dst,
                       int* __restrict__ cursor, int* __restrict__ csr) {
    int e = blockIdx.x * blockDim.x + threadIdx.x;
    if (e >= N_EDGES) return;
    int d = dst[e];
    int pos = atomicAdd(&cursor[d], 1);
    csr[pos] = src[e];
}

// -------------------------------------------------- weight split+transpose
// Whi/Wlo[n*Kp + k] = bf16 hi/lo of W[k*Nr + n]; zero outside [Kr x Nr].
// 7 matrices in one launch (blockIdx.y = job).
struct WJob { const float* W; ushort* hi; ushort* lo; int Kr, Nr, Kp; };
struct WJobs { WJob j[7]; };
__global__ void k_wsplit(WJobs jobs) {
    WJob jb = jobs.j[blockIdx.y];
    int idx = blockIdx.x * 256 + threadIdx.x;
    if (idx >= 128 * jb.Kp) return;
    int n = idx / jb.Kp, k = idx % jb.Kp;
    float w = (k < jb.Kr && n < jb.Nr) ? jb.W[(size_t)k * jb.Nr + n] : 0.f;
    ushort h = f2bf(w);
    jb.hi[idx] = h;
    jb.lo[idx] = f2bf(w - bf2f(h));
}

// x fp32 -> bf16 (6.4M elems, 4/thread)
__global__ void k_tobf16(const float* __restrict__ in, ushort* __restrict__ outb, int n) {
    int base = (blockIdx.x * 256 + threadIdx.x) * 4;
    if (base + 3 < n) {
        float4 v = *(const float4*)(in + base);
        uint2 o;
        o.x = packbf(v.x, v.y);
        o.y = packbf(v.z, v.w);
        *(uint2*)(outb + base) = o;
    } else {
        for (int i = base; i < n; ++i) outb[i] = f2bf(in[i]);
    }
}

// ------------------------------------------------------- gather (wave/node)
// out[v][f] = invdeg[v] * sum feat[src][f]; feat bf16 stride ldf; lane covers
// cols 2*lane, 2*lane+1. out: bf16 (outBf16) or fp32, stride ldo.
__global__ __launch_bounds__(256) void k_gatherb(
        const ushort* __restrict__ featb, int ldf,
        void* __restrict__ out, int ldo, int outBf16,
        const int* __restrict__ csr, const int* __restrict__ rs,
        const float* __restrict__ invdeg, int F) {
    int wid = (blockIdx.x * blockDim.x + threadIdx.x) >> 6;
    int lane = threadIdx.x & 63;
    if (wid >= N_NODES) return;
    int c0 = lane * 2;
    bool act = c0 < F;
    int s0 = rs[wid], s1 = rs[wid + 1];
    float acc0 = 0.f, acc1 = 0.f;
    int j = s0;
    for (; j + 8 <= s1; j += 8) {
        int idx[8];
#pragma unroll
        for (int u = 0; u < 8; ++u) idx[u] = csr[j + u];
        uint d[8];
#pragma unroll
        for (int u = 0; u < 8; ++u)
            d[u] = act ? *(const uint*)(featb + (size_t)idx[u] * ldf + c0) : 0u;
#pragma unroll
        for (int u = 0; u < 8; ++u) { acc0 += bflo(d[u]); acc1 += bfhi(d[u]); }
    }
    for (; j < s1; ++j) {
        uint d = act ? *(const uint*)(featb + (size_t)csr[j] * ldf + c0) : 0u;
        acc0 += bflo(d); acc1 += bfhi(d);
    }
    float sc = invdeg[wid];
    acc0 *= sc; acc1 *= sc;
    if (outBf16) {
        if (act) *(uint*)((ushort*)out + (size_t)wid * ldo + c0) = packbf(acc0, acc1);
    } else {
        float* o = (float*)out + (size_t)wid * ldo + c0;
        if (c0 < F)     o[0] = acc0;
        if (c0 + 1 < F) o[1] = acc1;
    }
}

// thread-per-node, F=5 fp32 (P4), unrolled by 4
__global__ __launch_bounds__(256) void k_gather5(
        const float* __restrict__ feat, float* __restrict__ out,
        const int* __restrict__ csr, const int* __restrict__ rs,
        const float* __restrict__ invdeg) {
    int v = blockIdx.x * blockDim.x + threadIdx.x;
    if (v >= N_NODES) return;
    int s0 = rs[v], s1 = rs[v + 1];
    float a[5] = {0.f, 0.f, 0.f, 0.f, 0.f};
    int j = s0;
    for (; j + 4 <= s1; j += 4) {
        const float* r0 = feat + (size_t)csr[j]     * 5;
        const float* r1 = feat + (size_t)csr[j + 1] * 5;
        const float* r2 = feat + (size_t)csr[j + 2] * 5;
        const float* r3 = feat + (size_t)csr[j + 3] * 5;
        float t0[5], t1[5], t2[5], t3[5];
#pragma unroll
        for (int c = 0; c < 5; ++c) { t0[c] = r0[c]; t1[c] = r1[c]; t2[c] = r2[c]; t3[c] = r3[c]; }
#pragma unroll
        for (int c = 0; c < 5; ++c) a[c] += (t0[c] + t1[c]) + (t2[c] + t3[c]);
    }
    for (; j < s1; ++j) {
        const float* r = feat + (size_t)csr[j] * 5;
#pragma unroll
        for (int c = 0; c < 5; ++c) a[c] += r[c];
    }
    float sc = invdeg[v];
    float* o = out + (size_t)v * 5;
#pragma unroll
    for (int c = 0; c < 5; ++c) o[c] = a[c] * sc;
}

// ------------------------------------------------------------ MFMA GEMM
// No LDS, no barriers. A bf16 [M x lda] (k-padded, pad x W-zero = 0);
// B pre-split/transposed/padded bf16 [128 x ldb]. fp32 accum, W hi+lo passes.
// Block = 4 waves; wave computes rows m0+wv*32..+31, cols n0..n0+63.
// Frag maps: A row=lane&15(+16), k=(lane>>4)*8+j; B row(n)=lane&15, same k;
// D col=lane&15, row=(lane>>4)*4+r  [m89-verified].
__global__ __launch_bounds__(256) void k_mm(
        const ushort* __restrict__ A1, int lda1, int kt1,
        const ushort* __restrict__ B1hi, const ushort* __restrict__ B1lo, int ldb1,
        const ushort* __restrict__ A2, int lda2, int kt2,
        const ushort* __restrict__ B2hi, const ushort* __restrict__ B2lo, int ldb2,
        const float* __restrict__ addend, int ldadd,
        const float* __restrict__ bias,
        void* __restrict__ C, int ldc, int N, int flags)  // 1=relu, 2=bf16 out
{
    const int M = N_NODES;
    int tid = threadIdx.x;
    int wv = tid >> 6, lane = tid & 63;
    int lr = lane & 15, lg = lane >> 4, lg8 = lg * 8;
    int m0 = blockIdx.x * 128, n0 = blockIdx.y * 64;
    int r0 = m0 + wv * 32 + lr;
    int ra0 = r0 < M ? r0 : M - 1;          // clamp: results write-guarded
    int ra1 = r0 + 16 < M ? r0 + 16 : M - 1;

    f32x4 acc[2][4];
#pragma unroll
    for (int i = 0; i < 2; ++i)
#pragma unroll
        for (int n = 0; n < 4; ++n) acc[i][n] = (f32x4){0.f, 0.f, 0.f, 0.f};

#pragma unroll
    for (int pass = 0; pass < 2; ++pass) {
        const ushort* A   = pass ? A2 : A1;
        const ushort* Bhi = pass ? B2hi : B1hi;
        const ushort* Blo = pass ? B2lo : B1lo;
        int lda = pass ? lda2 : lda1;
        int ldb = pass ? ldb2 : ldb1;
        int kts = pass ? kt2 : kt1;
        if (!A) continue;
        const ushort* pA0 = A + (size_t)ra0 * lda + lg8;
        const ushort* pA1 = A + (size_t)ra1 * lda + lg8;
        const ushort* pH  = Bhi + (size_t)(n0 + lr) * ldb + lg8;
        const ushort* pL  = Blo + (size_t)(n0 + lr) * ldb + lg8;
        int nstep = 16 * ldb;
        for (int kt = 0; kt < kts; ++kt, pA0 += 32, pA1 += 32, pH += 32, pL += 32) {
            bf16x8 a0 = *(const bf16x8*)pA0;
            bf16x8 a1 = *(const bf16x8*)pA1;
#pragma unroll
            for (int nf = 0; nf < 4; ++nf) {
                bf16x8 bh = *(const bf16x8*)(pH + nf * nstep);
                bf16x8 bl = *(const bf16x8*)(pL + nf * nstep);
                acc[0][nf] = __builtin_amdgcn_mfma_f32_16x16x32_bf16(a0, bh, acc[0][nf], 0, 0, 0);
                acc[1][nf] = __builtin_amdgcn_mfma_f32_16x16x32_bf16(a1, bh, acc[1][nf], 0, 0, 0);
                acc[0][nf] = __builtin_amdgcn_mfma_f32_16x16x32_bf16(a0, bl, acc[0][nf], 0, 0, 0);
                acc[1][nf] = __builtin_amdgcn_mfma_f32_16x16x32_bf16(a1, bl, acc[1][nf], 0, 0, 0);
            }
        }
    }
    int doRelu = flags & 1, outBf = flags & 2;
#pragma unroll
    for (int mi = 0; mi < 2; ++mi) {
#pragma unroll
        for (int r = 0; r < 4; ++r) {
            int gm = m0 + wv * 32 + mi * 16 + lg * 4 + r;
            if (gm >= M) continue;
#pragma unroll
            for (int nf = 0; nf < 4; ++nf) {
                int gn = n0 + nf * 16 + lr;
                if (gn >= N) continue;
                float v = acc[mi][nf][r];
                if (bias)   v += bias[gn];
                if (addend) v += addend[(size_t)gm * ldadd + gn];
                if (doRelu) v = fmaxf(v, 0.f);
                if (outBf) ((ushort*)C)[(size_t)gm * ldc + gn] = f2bf(v);
                else       ((float*)C)[(size_t)gm * ldc + gn] = v;
            }
        }
    }
}

// ------------------------------------------------ chunked segment-sum pooling
__global__ void k_poolb(const ushort* __restrict__ featb, int ldf, const int* __restrict__ gid,
                        float* __restrict__ pool, int F) {
    int base = blockIdx.x * 256;
    if (base >= N_NODES) return;
    int end = base + 256 < N_NODES ? base + 256 : N_NODES;
    int f = threadIdx.x;  // 128 threads
    float local = 0.f;
    int curg = gid[base];
    for (int v = base; v < end; ++v) {
        int g = gid[v];
        if (g != curg) {
            if (f < F) atomicAdd(&pool[curg * F + f], local);
            local = 0.f;
            curg = g;
        }
        if (f < F) local += bf2f(featb[(size_t)v * ldf + f]);
    }
    if (f < F) atomicAdd(&pool[curg * F + f], local);
}

__global__ void k_pool(const float* __restrict__ feat, const int* __restrict__ gid,
                       float* __restrict__ pool, int F) {
    int base = blockIdx.x * 256;
    if (base >= N_NODES) return;
    int end = base + 256 < N_NODES ? base + 256 : N_NODES;
    int f = threadIdx.x;
    float local = 0.f;
    int curg = gid[base];
    for (int v = base; v < end; ++v) {
        int g = gid[v];
        if (g != curg) {
            if (f < F) atomicAdd(&pool[curg * F + f], local);
            local = 0.f;
            curg = g;
        }
        if (f < F) local += feat[(size_t)v * F + f];
    }
    if (f < F) atomicAdd(&pool[curg * F + f], local);
}

// out[g][j] = (pooledH[g]@Ws4[:,j] + cnt_g*b4[j] + pooledA[g][j]) / max(cnt_g,1)
__global__ void k_final(const float* __restrict__ pooledH, const float* __restrict__ pooledA,
                        const float* __restrict__ Ws4, const float* __restrict__ b4,
                        const int* __restrict__ gstart, float* __restrict__ out) {
    int idx = threadIdx.x;
    if (idx >= N_GRAPHS * 5) return;
    int g = idx / 5, j = idx % 5;
    float cnt = (float)(gstart[g + 1] - gstart[g]);
    float s = 0.f;
    for (int k = 0; k < 103; ++k) s += pooledH[g * 103 + k] * Ws4[k * 5 + j];
    out[idx] = (s + cnt * b4[j] + pooledA[idx]) / fmaxf(cnt, 1.0f);
}

// --------------------------------------------------------------- launcher
extern "C" void kernel_launch(void* const* d_in, const int* in_sizes, int n_in,
                              void* d_out, int out_size, void* d_ws, size_t ws_size,
                              hipStream_t stream) {
    const float* x   = (const float*)d_in[0];
    const int*   src = (const int*)d_in[1];
    const int*   dst = (const int*)d_in[2];
    const int*   gid = (const int*)d_in[3];
    const float* Ws1 = (const float*)d_in[4],  *Wn1 = (const float*)d_in[5],  *b1 = (const float*)d_in[6];
    const float* Ws2 = (const float*)d_in[7],  *Wn2 = (const float*)d_in[8],  *b2 = (const float*)d_in[9];
    const float* Ws3 = (const float*)d_in[10], *Wn3 = (const float*)d_in[11], *b3 = (const float*)d_in[12];
    const float* Ws4 = (const float*)d_in[13], *Wn4 = (const float*)d_in[14], *b4 = (const float*)d_in[15];
    float* out = (float*)d_out;

    char* ws = (char*)d_ws;
    size_t off = 0;
    auto alloc = [&](size_t bytes) -> void* {
        void* p = ws + off;
        off += (bytes + 255) & ~(size_t)255;
        return p;
    };
    ushort* xb   = (ushort*)alloc((size_t)N_NODES * 64 * 2);
    ushort* agg1 = (ushort*)alloc((size_t)N_NODES * 64 * 2);
    ushort* S1   = (ushort*)alloc((size_t)N_NODES * 128 * 2);  // h1, then h3
    ushort* S2   = (ushort*)alloc((size_t)N_NODES * 128 * 2);  // P2, then P3
    ushort* S3   = (ushort*)alloc((size_t)N_NODES * 128 * 2);  // h2
    float*  aggF = (float*) alloc((size_t)N_NODES * 118 * 4);  // agg2, then agg3
    float*  P4   = (float*) alloc((size_t)N_NODES * 5 * 4);
    float*  agg4 = (float*) alloc((size_t)N_NODES * 5 * 4);
    int*   csr     = (int*)  alloc((size_t)N_EDGES * 4);
    int*   rs      = (int*)  alloc((size_t)(N_NODES + 1) * 4);
    int*   cursor  = (int*)  alloc((size_t)N_NODES * 4);
    int*   count   = (int*)  alloc((size_t)N_NODES * 4);
    int*   partials= (int*)  alloc(128 * 4);
    float* invdeg  = (float*)alloc((size_t)N_NODES * 4);
    int*   gstart  = (int*)  alloc((N_GRAPHS + 1) * 4);
    float* pooledH = (float*)alloc(N_GRAPHS * 103 * 4);
    float* pooledA = (float*)alloc(N_GRAPHS * 5 * 4);
    // weight tables: [128][Kp] bf16 hi/lo each
    auto walloc = [&](int Kp) { return (ushort*)alloc((size_t)128 * Kp * 2); };
    ushort *Ws1h = walloc(64),  *Ws1l = walloc(64);
    ushort *Wn1h = walloc(64),  *Wn1l = walloc(64);
    ushort *Wn2h = walloc(128), *Wn2l = walloc(128);
    ushort *Ws2h = walloc(128), *Ws2l = walloc(128);
    ushort *Wn3h = walloc(128), *Wn3l = walloc(128);
    ushort *Ws3h = walloc(128), *Ws3l = walloc(128);
    ushort *Wn4h = walloc(128), *Wn4l = walloc(128);

    hipMemsetAsync(count, 0, (size_t)N_NODES * 4, stream);
    hipMemsetAsync(pooledH, 0, N_GRAPHS * 103 * 4, stream);
    hipMemsetAsync(pooledA, 0, N_GRAPHS * 5 * 4, stream);

    WJobs jobs = {{
        {Ws1, Ws1h, Ws1l, 64, 128, 64},
        {Wn1, Wn1h, Wn1l, 64, 128, 64},
        {Wn2, Wn2h, Wn2l, 128, 118, 128},
        {Ws2, Ws2h, Ws2l, 128, 118, 128},
        {Wn3, Wn3h, Wn3l, 118, 103, 128},
        {Ws3, Ws3h, Ws3l, 118, 103, 128},
        {Wn4, Wn4h, Wn4l, 103, 5, 128},
    }};
    k_wsplit<<<dim3(64, 7), 256, 0, stream>>>(jobs);
    k_tobf16<<<(N_NODES * 64 / 4 + 255) / 256, 256, 0, stream>>>(x, xb, N_NODES * 64);

    const int SCAN_BLOCKS = (N_NODES + 1023) / 1024;  // 98
    k_count<<<(N_EDGES + 255) / 256, 256, 0, stream>>>(dst, count);
    k_scan1<<<SCAN_BLOCKS, 256, 0, stream>>>(count, rs, partials);
    k_scan2<<<1, 128, 0, stream>>>(partials, SCAN_BLOCKS);
    k_scan3<<<SCAN_BLOCKS, 256, 0, stream>>>(rs, cursor, partials);
    k_invdeg<<<(N_NODES + 255) / 256, 256, 0, stream>>>(count, invdeg);
    k_gbounds<<<1, 128, 0, stream>>>(gid, gstart);
    k_fill<<<(N_EDGES + 255) / 256, 256, 0, stream>>>(src, dst, cursor, csr);

    const int GATHER_BLOCKS = (N_NODES * 64 + 255) / 256;  // wave per node
    dim3 mm2((N_NODES + 127) / 128, 2);
    dim3 mm1((N_NODES + 127) / 128, 1);
    const int POOL_BLOCKS = (N_NODES + 255) / 256;

    // layer 1: gather x (bf16) -> agg1; dual-pass MFMA -> h1 (S1)
    k_gatherb<<<GATHER_BLOCKS, 256, 0, stream>>>(xb, 64, agg1, 64, 1, csr, rs, invdeg, 64);
    k_mm<<<mm2, 256, 0, stream>>>(xb, 64, 2, Ws1h, Ws1l, 64,
                                  agg1, 64, 2, Wn1h, Wn1l, 64,
                                  nullptr, 0, b1, S1, 128, 128, 1 | 2);

    // layer 2: P2 = h1@Wn2 (S2); gather -> aggF; h2 = relu(h1@Ws2 + aggF + b2) (S3)
    k_mm<<<mm2, 256, 0, stream>>>(S1, 128, 4, Wn2h, Wn2l, 128,
                                  nullptr, 0, 0, nullptr, nullptr, 0,
                                  nullptr, 0, nullptr, S2, 128, 118, 2);
    k_gatherb<<<GATHER_BLOCKS, 256, 0, stream>>>(S2, 128, aggF, 118, 0, csr, rs, invdeg, 118);
    k_mm<<<mm2, 256, 0, stream>>>(S1, 128, 4, Ws2h, Ws2l, 128,
                                  nullptr, 0, 0, nullptr, nullptr, 0,
                                  aggF, 118, b2, S3, 128, 118, 1 | 2);

    // layer 3: P3 = h2@Wn3 (S2); gather -> aggF; h3 = relu(h2@Ws3 + aggF + b3) (S1)
    k_mm<<<mm2, 256, 0, stream>>>(S3, 128, 4, Wn3h, Wn3l, 128,
                                  nullptr, 0, 0, nullptr, nullptr, 0,
                                  nullptr, 0, nullptr, S2, 128, 103, 2);
    k_gatherb<<<GATHER_BLOCKS, 256, 0, stream>>>(S2, 128, aggF, 103, 0, csr, rs, invdeg, 103);
    k_mm<<<mm2, 256, 0, stream>>>(S3, 128, 4, Ws3h, Ws3l, 128,
                                  nullptr, 0, 0, nullptr, nullptr, 0,
                                  aggF, 103, b3, S1, 128, 103, 1 | 2);

    // layer 4: P4 = h3@Wn4 (fp32); gather5 -> agg4; pooling + finalize
    k_mm<<<mm1, 256, 0, stream>>>(S1, 128, 4, Wn4h, Wn4l, 128,
                                  nullptr, 0, 0, nullptr, nullptr, 0,
                                  nullptr, 0, nullptr, P4, 5, 5, 0);
    k_gather5<<<(N_NODES + 255) / 256, 256, 0, stream>>>(P4, agg4, csr, rs, invdeg);

    k_poolb<<<POOL_BLOCKS, 128, 0, stream>>>(S1, 128, gid, pooledH, 103);
    k_pool<<<POOL_BLOCKS, 128, 0, stream>>>(agg4, gid, pooledA, 5);
    k_final<<<1, 320, 0, stream>>>(pooledH, pooledA, Ws4, b4, gstart, out);
}

// Round 12
// 927.746 us; speedup vs baseline: 4.2965x; 1.1082x over previous
//
#include <hip/hip_runtime.h>
#include <hip/hip_bf16.h>

#define N_NODES 100000
#define N_EDGES 1600000
#define N_GRAPHS 64

typedef __attribute__((ext_vector_type(8))) short bf16x8;  // 8 bf16 = 4 VGPR
typedef __attribute__((ext_vector_type(4))) float f32x4;   // MFMA C/D frag

__device__ __forceinline__ ushort f2bf(float f) {
    return __builtin_bit_cast(ushort, __float2bfloat16(f));
}
__device__ __forceinline__ float bf2f(ushort u) {
    return __builtin_bit_cast(float, (uint)u << 16);
}
__device__ __forceinline__ float bflo(uint d) { return __builtin_bit_cast(float, d << 16); }
__device__ __forceinline__ float bfhi(uint d) { return __builtin_bit_cast(float, d & 0xffff0000u); }
__device__ __forceinline__ uint packbf(float lo, float hi) {
    return ((uint)f2bf(hi) << 16) | (uint)f2bf(lo);
}

// ---------------------------------------------------------------- CSR build
// count + per-edge rank in one atomic pass (rank = return of atomicAdd)
__global__ void k_countrank(const int* __restrict__ dst, int* __restrict__ count,
                            int* __restrict__ rank) {
    int e = blockIdx.x * blockDim.x + threadIdx.x;
    if (e < N_EDGES) rank[e] = atomicAdd(&count[dst[e]], 1);
}

__global__ void k_scan1(const int* __restrict__ cnt, int* __restrict__ rs, int* __restrict__ partials) {
    __shared__ int s[256];
    int b = blockIdx.x, t = threadIdx.x;
    int base = b * 1024 + t * 4;
    int v0 = 0, v1 = 0, v2 = 0, v3 = 0;
    if (base + 3 < N_NODES) {
        int4 q = *(const int4*)(cnt + base);
        v0 = q.x; v1 = q.y; v2 = q.z; v3 = q.w;
    } else {
        if (base     < N_NODES) v0 = cnt[base];
        if (base + 1 < N_NODES) v1 = cnt[base + 1];
        if (base + 2 < N_NODES) v2 = cnt[base + 2];
        if (base + 3 < N_NODES) v3 = cnt[base + 3];
    }
    int tsum = v0 + v1 + v2 + v3;
    s[t] = tsum; __syncthreads();
    for (int off = 1; off < 256; off <<= 1) {
        int x = (t >= off) ? s[t - off] : 0;
        __syncthreads();
        s[t] += x;
        __syncthreads();
    }
    int excl = s[t] - tsum;
    if (base     < N_NODES) rs[base]     = excl;
    excl += v0;
    if (base + 1 < N_NODES) rs[base + 1] = excl;
    excl += v1;
    if (base + 2 < N_NODES) rs[base + 2] = excl;
    excl += v2;
    if (base + 3 < N_NODES) rs[base + 3] = excl;
    if (t == 255) partials[b] = s[255];
}

__global__ void k_scan2(int* __restrict__ partials, int nb) {
    __shared__ int s[128];
    int t = threadIdx.x;
    int v = (t < nb) ? partials[t] : 0;
    s[t] = v; __syncthreads();
    for (int off = 1; off < 128; off <<= 1) {
        int x = (t >= off) ? s[t - off] : 0;
        __syncthreads();
        s[t] += x;
        __syncthreads();
    }
    if (t < nb) partials[t] = s[t] - v;  // exclusive
}

__global__ void k_scan3(int* __restrict__ rs, const int* __restrict__ partials) {
    int b = blockIdx.x, t = threadIdx.x;
    int off = partials[b];
    int base = b * 1024 + t * 4;
#pragma unroll
    for (int i = 0; i < 4; ++i) {
        int idx = base + i;
        if (idx < N_NODES) rs[idx] += off;
    }
    if (b == 0 && t == 0) rs[N_NODES] = N_EDGES;
}

__global__ void k_invdeg(const int* __restrict__ count, float* __restrict__ invdeg) {
    int v = blockIdx.x * blockDim.x + threadIdx.x;
    if (v >= N_NODES) return;
    int d = count[v];
    invdeg[v] = d > 0 ? 1.0f / (float)d : 0.0f;
}

__global__ void k_gbounds(const int* __restrict__ gid, int* __restrict__ gstart) {
    int g = threadIdx.x;
    if (g > N_GRAPHS) return;
    int lo = 0, hi = N_NODES;
    while (lo < hi) {
        int mid = (lo + hi) >> 1;
        if (gid[mid] < g) lo = mid + 1; else hi = mid;
    }
    gstart[g] = lo;
}

// atomic-free fill: position = rs[dst] + rank
__global__ void k_scatter(const int* __restrict__ src, const int* __restrict__ dst,
                          const int* __restrict__ rank, const int* __restrict__ rs,
                          int* __restrict__ csr) {
    int e = blockIdx.x * blockDim.x + threadIdx.x;
    if (e >= N_EDGES) return;
    csr[rs[dst[e]] + rank[e]] = src[e];
}

// -------------------------------------------------- weight split+transpose
// Whi/Wlo[n*Kp + k] = bf16 hi/lo of W[k*Nr + n]; zero outside [Kr x Nr].
struct WJob { const float* W; ushort* hi; ushort* lo; int Kr, Nr, Kp; };
struct WJobs { WJob j[7]; };
__global__ void k_wsplit(WJobs jobs) {
    WJob jb = jobs.j[blockIdx.y];
    int idx = blockIdx.x * 256 + threadIdx.x;
    if (idx >= 128 * jb.Kp) return;
    int n = idx / jb.Kp, k = idx % jb.Kp;
    float w = (k < jb.Kr && n < jb.Nr) ? jb.W[(size_t)k * jb.Nr + n] : 0.f;
    ushort h = f2bf(w);
    jb.hi[idx] = h;
    jb.lo[idx] = f2bf(w - bf2f(h));
}

// x fp32 -> bf16 (6.4M elems, 4/thread)
__global__ void k_tobf16(const float* __restrict__ in, ushort* __restrict__ outb, int n) {
    int base = (blockIdx.x * 256 + threadIdx.x) * 4;
    if (base + 3 < n) {
        float4 v = *(const float4*)(in + base);
        uint2 o;
        o.x = packbf(v.x, v.y);
        o.y = packbf(v.z, v.w);
        *(uint2*)(outb + base) = o;
    } else {
        for (int i = base; i < n; ++i) outb[i] = f2bf(in[i]);
    }
}

// ------------------------------------------------------- gather (wave/node)
// out[v][f] = invdeg[v] * sum feat[src][f]; feat bf16 stride ldf; lane covers
// cols 2*lane, 2*lane+1. out: bf16 (outBf16) or fp32, stride ldo.
__global__ __launch_bounds__(256) void k_gatherb(
        const ushort* __restrict__ featb, int ldf,
        void* __restrict__ out, int ldo, int outBf16,
        const int* __restrict__ csr, const int* __restrict__ rs,
        const float* __restrict__ invdeg, int F) {
    int wid = (blockIdx.x * blockDim.x + threadIdx.x) >> 6;
    int lane = threadIdx.x & 63;
    if (wid >= N_NODES) return;
    int c0 = lane * 2;
    bool act = c0 < F;
    int s0 = rs[wid], s1 = rs[wid + 1];
    float acc0 = 0.f, acc1 = 0.f;
    int j = s0;
    for (; j + 8 <= s1; j += 8) {
        int idx[8];
#pragma unroll
        for (int u = 0; u < 8; ++u) idx[u] = csr[j + u];
        uint d[8];
#pragma unroll
        for (int u = 0; u < 8; ++u)
            d[u] = act ? *(const uint*)(featb + (size_t)idx[u] * ldf + c0) : 0u;
#pragma unroll
        for (int u = 0; u < 8; ++u) { acc0 += bflo(d[u]); acc1 += bfhi(d[u]); }
    }
    for (; j < s1; ++j) {
        uint d = act ? *(const uint*)(featb + (size_t)csr[j] * ldf + c0) : 0u;
        acc0 += bflo(d); acc1 += bfhi(d);
    }
    float sc = invdeg[wid];
    acc0 *= sc; acc1 *= sc;
    if (outBf16) {
        if (act) *(uint*)((ushort*)out + (size_t)wid * ldo + c0) = packbf(acc0, acc1);
    } else {
        float* o = (float*)out + (size_t)wid * ldo + c0;
        if (c0 < F)     o[0] = acc0;
        if (c0 + 1 < F) o[1] = acc1;
    }
}

// F=64 bf16->bf16 gather, 2 nodes per wave (half-wave each): no idle lanes
__global__ __launch_bounds__(256) void k_gather64x2(
        const ushort* __restrict__ featb, ushort* __restrict__ out,
        const int* __restrict__ csr, const int* __restrict__ rs,
        const float* __restrict__ invdeg) {
    int w = (blockIdx.x * blockDim.x + threadIdx.x) >> 6;
    int lane = threadIdx.x & 63;
    int v = w * 2 + (lane >> 5);
    if (v >= N_NODES) return;
    int c0 = (lane & 31) * 2;
    int s0 = rs[v], s1 = rs[v + 1];
    float acc0 = 0.f, acc1 = 0.f;
    int j = s0;
    for (; j + 8 <= s1; j += 8) {
        int idx[8];
#pragma unroll
        for (int u = 0; u < 8; ++u) idx[u] = csr[j + u];
        uint d[8];
#pragma unroll
        for (int u = 0; u < 8; ++u)
            d[u] = *(const uint*)(featb + (size_t)idx[u] * 64 + c0);
#pragma unroll
        for (int u = 0; u < 8; ++u) { acc0 += bflo(d[u]); acc1 += bfhi(d[u]); }
    }
    for (; j < s1; ++j) {
        uint d = *(const uint*)(featb + (size_t)csr[j] * 64 + c0);
        acc0 += bflo(d); acc1 += bfhi(d);
    }
    float sc = invdeg[v];
    *(uint*)(out + (size_t)v * 64 + c0) = packbf(acc0 * sc, acc1 * sc);
}

// thread-per-node, F=5 fp32 (P4), unrolled by 4
__global__ __launch_bounds__(256) void k_gather5(
        const float* __restrict__ feat, float* __restrict__ out,
        const int* __restrict__ csr, const int* __restrict__ rs,
        const float* __restrict__ invdeg) {
    int v = blockIdx.x * blockDim.x + threadIdx.x;
    if (v >= N_NODES) return;
    int s0 = rs[v], s1 = rs[v + 1];
    float a[5] = {0.f, 0.f, 0.f, 0.f, 0.f};
    int j = s0;
    for (; j + 4 <= s1; j += 4) {
        const float* r0 = feat + (size_t)csr[j]     * 5;
        const float* r1 = feat + (size_t)csr[j + 1] * 5;
        const float* r2 = feat + (size_t)csr[j + 2] * 5;
        const float* r3 = feat + (size_t)csr[j + 3] * 5;
        float t0[5], t1[5], t2[5], t3[5];
#pragma unroll
        for (int c = 0; c < 5; ++c) { t0[c] = r0[c]; t1[c] = r1[c]; t2[c] = r2[c]; t3[c] = r3[c]; }
#pragma unroll
        for (int c = 0; c < 5; ++c) a[c] += (t0[c] + t1[c]) + (t2[c] + t3[c]);
    }
    for (; j < s1; ++j) {
        const float* r = feat + (size_t)csr[j] * 5;
#pragma unroll
        for (int c = 0; c < 5; ++c) a[c] += r[c];
    }
    float sc = invdeg[v];
    float* o = out + (size_t)v * 5;
#pragma unroll
    for (int c = 0; c < 5; ++c) o[c] = a[c] * sc;
}

// ------------------------------------------------------------ MFMA GEMM
// No LDS, no barriers. A bf16 [M x lda] (k-padded, pad x W-zero = 0);
// B pre-split/transposed/padded bf16 [128 x ldb]. fp32 accum, W hi+lo passes.
// Block = 4 waves; wave computes rows m0+wv*32..+31, cols n0..n0+63.
// Frag maps: A row=lane&15(+16), k=(lane>>4)*8+j; B row(n)=lane&15, same k;
// D col=lane&15, row=(lane>>4)*4+r  [m89-verified].
__global__ __launch_bounds__(256) void k_mm(
        const ushort* __restrict__ A1, int lda1, int kt1,
        const ushort* __restrict__ B1hi, const ushort* __restrict__ B1lo, int ldb1,
        const ushort* __restrict__ A2, int lda2, int kt2,
        const ushort* __restrict__ B2hi, const ushort* __restrict__ B2lo, int ldb2,
        const float* __restrict__ addend, int ldadd,
        const float* __restrict__ bias,
        void* __restrict__ C, int ldc, int N, int flags)  // 1=relu, 2=bf16 out
{
    const int M = N_NODES;
    int tid = threadIdx.x;
    int wv = tid >> 6, lane = tid & 63;
    int lr = lane & 15, lg = lane >> 4, lg8 = lg * 8;
    int m0 = blockIdx.x * 128, n0 = blockIdx.y * 64;
    int r0 = m0 + wv * 32 + lr;
    int ra0 = r0 < M ? r0 : M - 1;          // clamp: results write-guarded
    int ra1 = r0 + 16 < M ? r0 + 16 : M - 1;

    f32x4 acc[2][4];
#pragma unroll
    for (int i = 0; i < 2; ++i)
#pragma unroll
        for (int n = 0; n < 4; ++n) acc[i][n] = (f32x4){0.f, 0.f, 0.f, 0.f};

#pragma unroll
    for (int pass = 0; pass < 2; ++pass) {
        const ushort* A   = pass ? A2 : A1;
        const ushort* Bhi = pass ? B2hi : B1hi;
        const ushort* Blo = pass ? B2lo : B1lo;
        int lda = pass ? lda2 : lda1;
        int ldb = pass ? ldb2 : ldb1;
        int kts = pass ? kt2 : kt1;
        if (!A) continue;
        const ushort* pA0 = A + (size_t)ra0 * lda + lg8;
        const ushort* pA1 = A + (size_t)ra1 * lda + lg8;
        const ushort* pH  = Bhi + (size_t)(n0 + lr) * ldb + lg8;
        const ushort* pL  = Blo + (size_t)(n0 + lr) * ldb + lg8;
        int nstep = 16 * ldb;
        for (int kt = 0; kt < kts; ++kt, pA0 += 32, pA1 += 32, pH += 32, pL += 32) {
            bf16x8 a0 = *(const bf16x8*)pA0;
            bf16x8 a1 = *(const bf16x8*)pA1;
#pragma unroll
            for (int nf = 0; nf < 4; ++nf) {
                bf16x8 bh = *(const bf16x8*)(pH + nf * nstep);
                bf16x8 bl = *(const bf16x8*)(pL + nf * nstep);
                acc[0][nf] = __builtin_amdgcn_mfma_f32_16x16x32_bf16(a0, bh, acc[0][nf], 0, 0, 0);
                acc[1][nf] = __builtin_amdgcn_mfma_f32_16x16x32_bf16(a1, bh, acc[1][nf], 0, 0, 0);
                acc[0][nf] = __builtin_amdgcn_mfma_f32_16x16x32_bf16(a0, bl, acc[0][nf], 0, 0, 0);
                acc[1][nf] = __builtin_amdgcn_mfma_f32_16x16x32_bf16(a1, bl, acc[1][nf], 0, 0, 0);
            }
        }
    }
    int doRelu = flags & 1, outBf = flags & 2;
#pragma unroll
    for (int mi = 0; mi < 2; ++mi) {
#pragma unroll
        for (int r = 0; r < 4; ++r) {
            int gm = m0 + wv * 32 + mi * 16 + lg * 4 + r;
            if (gm >= M) continue;
#pragma unroll
            for (int nf = 0; nf < 4; ++nf) {
                int gn = n0 + nf * 16 + lr;
                if (gn >= N) continue;
                float v = acc[mi][nf][r];
                if (bias)   v += bias[gn];
                if (addend) v += addend[(size_t)gm * ldadd + gn];
                if (doRelu) v = fmaxf(v, 0.f);
                if (outBf) ((ushort*)C)[(size_t)gm * ldc + gn] = f2bf(v);
                else       ((float*)C)[(size_t)gm * ldc + gn] = v;
            }
        }
    }
}

// ------------------------------------------------ chunked segment-sum pooling
__global__ void k_poolb(const ushort* __restrict__ featb, int ldf, const int* __restrict__ gid,
                        float* __restrict__ pool, int F) {
    int base = blockIdx.x * 256;
    if (base >= N_NODES) return;
    int end = base + 256 < N_NODES ? base + 256 : N_NODES;
    int f = threadIdx.x;  // 128 threads
    float local = 0.f;
    int curg = gid[base];
    for (int v = base; v < end; ++v) {
        int g = gid[v];
        if (g != curg) {
            if (f < F) atomicAdd(&pool[curg * F + f], local);
            local = 0.f;
            curg = g;
        }
        if (f < F) local += bf2f(featb[(size_t)v * ldf + f]);
    }
    if (f < F) atomicAdd(&pool[curg * F + f], local);
}

__global__ void k_pool(const float* __restrict__ feat, const int* __restrict__ gid,
                       float* __restrict__ pool, int F) {
    int base = blockIdx.x * 256;
    if (base >= N_NODES) return;
    int end = base + 256 < N_NODES ? base + 256 : N_NODES;
    int f = threadIdx.x;
    float local = 0.f;
    int curg = gid[base];
    for (int v = base; v < end; ++v) {
        int g = gid[v];
        if (g != curg) {
            if (f < F) atomicAdd(&pool[curg * F + f], local);
            local = 0.f;
            curg = g;
        }
        if (f < F) local += feat[(size_t)v * F + f];
    }
    if (f < F) atomicAdd(&pool[curg * F + f], local);
}

// out[g][j] = (pooledH[g]@Ws4[:,j] + cnt_g*b4[j] + pooledA[g][j]) / max(cnt_g,1)
__global__ void k_final(const float* __restrict__ pooledH, const float* __restrict__ pooledA,
                        const float* __restrict__ Ws4, const float* __restrict__ b4,
                        const int* __restrict__ gstart, float* __restrict__ out) {
    int idx = threadIdx.x;
    if (idx >= N_GRAPHS * 5) return;
    int g = idx / 5, j = idx % 5;
    float cnt = (float)(gstart[g + 1] - gstart[g]);
    float s = 0.f;
    for (int k = 0; k < 103; ++k) s += pooledH[g * 103 + k] * Ws4[k * 5 + j];
    out[idx] = (s + cnt * b4[j] + pooledA[idx]) / fmaxf(cnt, 1.0f);
}

// --------------------------------------------------------------- launcher
extern "C" void kernel_launch(void* const* d_in, const int* in_sizes, int n_in,
                              void* d_out, int out_size, void* d_ws, size_t ws_size,
                              hipStream_t stream) {
    const float* x   = (const float*)d_in[0];
    const int*   src = (const int*)d_in[1];
    const int*   dst = (const int*)d_in[2];
    const int*   gid = (const int*)d_in[3];
    const float* Ws1 = (const float*)d_in[4],  *Wn1 = (const float*)d_in[5],  *b1 = (const float*)d_in[6];
    const float* Ws2 = (const float*)d_in[7],  *Wn2 = (const float*)d_in[8],  *b2 = (const float*)d_in[9];
    const float* Ws3 = (const float*)d_in[10], *Wn3 = (const float*)d_in[11], *b3 = (const float*)d_in[12];
    const float* Ws4 = (const float*)d_in[13], *Wn4 = (const float*)d_in[14], *b4 = (const float*)d_in[15];
    float* out = (float*)d_out;

    char* ws = (char*)d_ws;
    size_t off = 0;
    auto alloc = [&](size_t bytes) -> void* {
        void* p = ws + off;
        off += (bytes + 255) & ~(size_t)255;
        return p;
    };
    ushort* xb   = (ushort*)alloc((size_t)N_NODES * 64 * 2);
    ushort* agg1 = (ushort*)alloc((size_t)N_NODES * 64 * 2);
    ushort* S1   = (ushort*)alloc((size_t)N_NODES * 128 * 2);  // h1, then h3
    ushort* S2   = (ushort*)alloc((size_t)N_NODES * 128 * 2);  // P2, then P3
    ushort* S3   = (ushort*)alloc((size_t)N_NODES * 128 * 2);  // h2
    float*  aggF = (float*) alloc((size_t)N_NODES * 118 * 4);  // agg2, then agg3
    float*  P4   = (float*) alloc((size_t)N_NODES * 5 * 4);
    float*  agg4 = (float*) alloc((size_t)N_NODES * 5 * 4);
    int*   csr     = (int*)  alloc((size_t)N_EDGES * 4);
    int*   rank    = (int*)  alloc((size_t)N_EDGES * 4);
    int*   rs      = (int*)  alloc((size_t)(N_NODES + 1) * 4);
    int*   count   = (int*)  alloc((size_t)N_NODES * 4);
    int*   partials= (int*)  alloc(128 * 4);
    float* invdeg  = (float*)alloc((size_t)N_NODES * 4);
    int*   gstart  = (int*)  alloc((N_GRAPHS + 1) * 4);
    float* pooledH = (float*)alloc(N_GRAPHS * 103 * 4);
    float* pooledA = (float*)alloc(N_GRAPHS * 5 * 4);
    // weight tables: [128][Kp] bf16 hi/lo each
    auto walloc = [&](int Kp) { return (ushort*)alloc((size_t)128 * Kp * 2); };
    ushort *Ws1h = walloc(64),  *Ws1l = walloc(64);
    ushort *Wn1h = walloc(64),  *Wn1l = walloc(64);
    ushort *Wn2h = walloc(128), *Wn2l = walloc(128);
    ushort *Ws2h = walloc(128), *Ws2l = walloc(128);
    ushort *Wn3h = walloc(128), *Wn3l = walloc(128);
    ushort *Ws3h = walloc(128), *Ws3l = walloc(128);
    ushort *Wn4h = walloc(128), *Wn4l = walloc(128);

    hipMemsetAsync(count, 0, (size_t)N_NODES * 4, stream);
    hipMemsetAsync(pooledH, 0, N_GRAPHS * 103 * 4, stream);
    hipMemsetAsync(pooledA, 0, N_GRAPHS * 5 * 4, stream);

    WJobs jobs = {{
        {Ws1, Ws1h, Ws1l, 64, 128, 64},
        {Wn1, Wn1h, Wn1l, 64, 128, 64},
        {Wn2, Wn2h, Wn2l, 128, 118, 128},
        {Ws2, Ws2h, Ws2l, 128, 118, 128},
        {Wn3, Wn3h, Wn3l, 118, 103, 128},
        {Ws3, Ws3h, Ws3l, 118, 103, 128},
        {Wn4, Wn4h, Wn4l, 103, 5, 128},
    }};
    k_wsplit<<<dim3(64, 7), 256, 0, stream>>>(jobs);
    k_tobf16<<<(N_NODES * 64 / 4 + 255) / 256, 256, 0, stream>>>(x, xb, N_NODES * 64);

    const int SCAN_BLOCKS = (N_NODES + 1023) / 1024;  // 98
    k_countrank<<<(N_EDGES + 255) / 256, 256, 0, stream>>>(dst, count, rank);
    k_scan1<<<SCAN_BLOCKS, 256, 0, stream>>>(count, rs, partials);
    k_scan2<<<1, 128, 0, stream>>>(partials, SCAN_BLOCKS);
    k_scan3<<<SCAN_BLOCKS, 256, 0, stream>>>(rs, partials);
    k_invdeg<<<(N_NODES + 255) / 256, 256, 0, stream>>>(count, invdeg);
    k_gbounds<<<1, 128, 0, stream>>>(gid, gstart);
    k_scatter<<<(N_EDGES + 255) / 256, 256, 0, stream>>>(src, dst, rank, rs, csr);

    const int GATHER_BLOCKS = (N_NODES * 64 + 255) / 256;       // wave per node
    const int GATHER2_BLOCKS = (N_NODES * 32 + 255) / 256;      // 2 nodes/wave
    dim3 mm2((N_NODES + 127) / 128, 2);
    dim3 mm1((N_NODES + 127) / 128, 1);
    const int POOL_BLOCKS = (N_NODES + 255) / 256;

    // layer 1: gather x (bf16) -> agg1 (2 nodes/wave); dual-pass MFMA -> h1 (S1)
    k_gather64x2<<<GATHER2_BLOCKS, 256, 0, stream>>>(xb, agg1, csr, rs, invdeg);
    k_mm<<<mm2, 256, 0, stream>>>(xb, 64, 2, Ws1h, Ws1l, 64,
                                  agg1, 64, 2, Wn1h, Wn1l, 64,
                                  nullptr, 0, b1, S1, 128, 128, 1 | 2);

    // layer 2: P2 = h1@Wn2 (S2); gather -> aggF; h2 = relu(h1@Ws2 + aggF + b2) (S3)
    k_mm<<<mm2, 256, 0, stream>>>(S1, 128, 4, Wn2h, Wn2l, 128,
                                  nullptr, 0, 0, nullptr, nullptr, 0,
                                  nullptr, 0, nullptr, S2, 128, 118, 2);
    k_gatherb<<<GATHER_BLOCKS, 256, 0, stream>>>(S2, 128, aggF, 118, 0, csr, rs, invdeg, 118);
    k_mm<<<mm2, 256, 0, stream>>>(S1, 128, 4, Ws2h, Ws2l, 128,
                                  nullptr, 0, 0, nullptr, nullptr, 0,
                                  aggF, 118, b2, S3, 128, 118, 1 | 2);

    // layer 3: P3 = h2@Wn3 (S2); gather -> aggF; h3 = relu(h2@Ws3 + aggF + b3) (S1)
    k_mm<<<mm2, 256, 0, stream>>>(S3, 128, 4, Wn3h, Wn3l, 128,
                                  nullptr, 0, 0, nullptr, nullptr, 0,
                                  nullptr, 0, nullptr, S2, 128, 103, 2);
    k_gatherb<<<GATHER_BLOCKS, 256, 0, stream>>>(S2, 128, aggF, 103, 0, csr, rs, invdeg, 103);
    k_mm<<<mm2, 256, 0, stream>>>(S3, 128, 4, Ws3h, Ws3l, 128,
                                  nullptr, 0, 0, nullptr, nullptr, 0,
                                  aggF, 103, b3, S1, 128, 103, 1 | 2);

    // layer 4: P4 = h3@Wn4 (fp32); gather5 -> agg4; pooling + finalize
    k_mm<<<mm1, 256, 0, stream>>>(S1, 128, 4, Wn4h, Wn4l, 128,
                                  nullptr, 0, 0, nullptr, nullptr, 0,
                                  nullptr, 0, nullptr, P4, 5, 5, 0);
    k_gather5<<<(N_NODES + 255) / 256, 256, 0, stream>>>(P4, agg4, csr, rs, invdeg);

    k_poolb<<<POOL_BLOCKS, 128, 0, stream>>>(S1, 128, gid, pooledH, 103);
    k_pool<<<POOL_BLOCKS, 128, 0, stream>>>(agg4, gid, pooledA, 5);
    k_final<<<1, 320, 0, stream>>>(pooledH, pooledA, Ws4, b4, gstart, out);
}

// Round 15
// 846.000 us; speedup vs baseline: 4.7117x; 1.0966x over previous
//
#include <hip/hip_runtime.h>
#include <hip/hip_bf16.h>

#define N_NODES 100000
#define N_EDGES 1600000
#define N_GRAPHS 64

typedef __attribute__((ext_vector_type(8))) short bf16x8;  // 8 bf16 = 4 VGPR
typedef __attribute__((ext_vector_type(4))) float f32x4;   // MFMA C/D frag

__device__ __forceinline__ ushort f2bf(float f) {
    return __builtin_bit_cast(ushort, __float2bfloat16(f));
}
__device__ __forceinline__ float bf2f(ushort u) {
    return __builtin_bit_cast(float, (uint)u << 16);
}
__device__ __forceinline__ float bflo(uint d) { return __builtin_bit_cast(float, d << 16); }
__device__ __forceinline__ float bfhi(uint d) { return __builtin_bit_cast(float, d & 0xffff0000u); }
__device__ __forceinline__ uint packbf(float lo, float hi) {
    return ((uint)f2bf(hi) << 16) | (uint)f2bf(lo);
}

// ---------------------------------------------------------------- CSR build
// count + per-edge rank in one atomic pass (rank = return of atomicAdd)
__global__ void k_countrank(const int* __restrict__ dst, int* __restrict__ count,
                            int* __restrict__ rank) {
    int e = blockIdx.x * blockDim.x + threadIdx.x;
    if (e < N_EDGES) rank[e] = atomicAdd(&count[dst[e]], 1);
}

__global__ void k_scan1(const int* __restrict__ cnt, int* __restrict__ rs, int* __restrict__ partials) {
    __shared__ int s[256];
    int b = blockIdx.x, t = threadIdx.x;
    int base = b * 1024 + t * 4;
    int v0 = 0, v1 = 0, v2 = 0, v3 = 0;
    if (base + 3 < N_NODES) {
        int4 q = *(const int4*)(cnt + base);
        v0 = q.x; v1 = q.y; v2 = q.z; v3 = q.w;
    } else {
        if (base     < N_NODES) v0 = cnt[base];
        if (base + 1 < N_NODES) v1 = cnt[base + 1];
        if (base + 2 < N_NODES) v2 = cnt[base + 2];
        if (base + 3 < N_NODES) v3 = cnt[base + 3];
    }
    int tsum = v0 + v1 + v2 + v3;
    s[t] = tsum; __syncthreads();
    for (int off = 1; off < 256; off <<= 1) {
        int x = (t >= off) ? s[t - off] : 0;
        __syncthreads();
        s[t] += x;
        __syncthreads();
    }
    int excl = s[t] - tsum;
    if (base     < N_NODES) rs[base]     = excl;
    excl += v0;
    if (base + 1 < N_NODES) rs[base + 1] = excl;
    excl += v1;
    if (base + 2 < N_NODES) rs[base + 2] = excl;
    excl += v2;
    if (base + 3 < N_NODES) rs[base + 3] = excl;
    if (t == 255) partials[b] = s[255];
}

__global__ void k_scan2(int* __restrict__ partials, int nb) {
    __shared__ int s[128];
    int t = threadIdx.x;
    int v = (t < nb) ? partials[t] : 0;
    s[t] = v; __syncthreads();
    for (int off = 1; off < 128; off <<= 1) {
        int x = (t >= off) ? s[t - off] : 0;
        __syncthreads();
        s[t] += x;
        __syncthreads();
    }
    if (t < nb) partials[t] = s[t] - v;  // exclusive
}

__global__ void k_scan3(int* __restrict__ rs, const int* __restrict__ partials) {
    int b = blockIdx.x, t = threadIdx.x;
    int off = partials[b];
    int base = b * 1024 + t * 4;
#pragma unroll
    for (int i = 0; i < 4; ++i) {
        int idx = base + i;
        if (idx < N_NODES) rs[idx] += off;
    }
    if (b == 0 && t == 0) rs[N_NODES] = N_EDGES;
}

__global__ void k_invdeg(const int* __restrict__ count, float* __restrict__ invdeg) {
    int v = blockIdx.x * blockDim.x + threadIdx.x;
    if (v >= N_NODES) return;
    int d = count[v];
    invdeg[v] = d > 0 ? 1.0f / (float)d : 0.0f;
}

__global__ void k_gbounds(const int* __restrict__ gid, int* __restrict__ gstart) {
    int g = threadIdx.x;
    if (g > N_GRAPHS) return;
    int lo = 0, hi = N_NODES;
    while (lo < hi) {
        int mid = (lo + hi) >> 1;
        if (gid[mid] < g) lo = mid + 1; else hi = mid;
    }
    gstart[g] = lo;
}

// atomic-free fill: position = rs[dst] + rank
__global__ void k_scatter(const int* __restrict__ src, const int* __restrict__ dst,
                          const int* __restrict__ rank, const int* __restrict__ rs,
                          int* __restrict__ csr) {
    int e = blockIdx.x * blockDim.x + threadIdx.x;
    if (e >= N_EDGES) return;
    csr[rs[dst[e]] + rank[e]] = src[e];
}

// -------------------------------------------------- weight split+transpose
// Whi/Wlo[n*Kp + k] = bf16 hi/lo of W[k*Nr + n]; zero outside [Kr x Nr].
struct WJob { const float* W; ushort* hi; ushort* lo; int Kr, Nr, Kp; };
struct WJobs { WJob j[7]; };
__global__ void k_wsplit(WJobs jobs) {
    WJob jb = jobs.j[blockIdx.y];
    int idx = blockIdx.x * 256 + threadIdx.x;
    if (idx >= 128 * jb.Kp) return;
    int n = idx / jb.Kp, k = idx % jb.Kp;
    float w = (k < jb.Kr && n < jb.Nr) ? jb.W[(size_t)k * jb.Nr + n] : 0.f;
    ushort h = f2bf(w);
    jb.hi[idx] = h;
    jb.lo[idx] = f2bf(w - bf2f(h));
}

// x fp32 -> bf16 (6.4M elems, 4/thread)
__global__ void k_tobf16(const float* __restrict__ in, ushort* __restrict__ outb, int n) {
    int base = (blockIdx.x * 256 + threadIdx.x) * 4;
    if (base + 3 < n) {
        float4 v = *(const float4*)(in + base);
        uint2 o;
        o.x = packbf(v.x, v.y);
        o.y = packbf(v.z, v.w);
        *(uint2*)(outb + base) = o;
    } else {
        for (int i = base; i < n; ++i) outb[i] = f2bf(in[i]);
    }
}

// ------------------------------------------------------- gather (wave/node)
// out[v][f] = invdeg[v] * sum feat[src][f]; feat bf16 stride ldf; lane covers
// cols 2*lane, 2*lane+1. outBf16: writes FULL ldo row (pad cols zeroed).
__global__ __launch_bounds__(256) void k_gatherb(
        const ushort* __restrict__ featb, int ldf,
        void* __restrict__ out, int ldo, int outBf16,
        const int* __restrict__ csr, const int* __restrict__ rs,
        const float* __restrict__ invdeg, int F) {
    int wid = (blockIdx.x * blockDim.x + threadIdx.x) >> 6;
    int lane = threadIdx.x & 63;
    if (wid >= N_NODES) return;
    int c0 = lane * 2;
    bool act = c0 < F;
    int s0 = rs[wid], s1 = rs[wid + 1];
    float acc0 = 0.f, acc1 = 0.f;
    int j = s0;
    for (; j + 8 <= s1; j += 8) {
        int idx[8];
#pragma unroll
        for (int u = 0; u < 8; ++u) idx[u] = csr[j + u];
        uint d[8];
#pragma unroll
        for (int u = 0; u < 8; ++u)
            d[u] = act ? *(const uint*)(featb + (size_t)idx[u] * ldf + c0) : 0u;
#pragma unroll
        for (int u = 0; u < 8; ++u) { acc0 += bflo(d[u]); acc1 += bfhi(d[u]); }
    }
    for (; j < s1; ++j) {
        uint d = act ? *(const uint*)(featb + (size_t)csr[j] * ldf + c0) : 0u;
        acc0 += bflo(d); acc1 += bfhi(d);
    }
    float sc = invdeg[wid];
    acc0 *= sc; acc1 *= sc;
    if (outBf16) {
        if (c0 < ldo)  // write full row incl. zeroed pads (acc=0 for inactive)
            *(uint*)((ushort*)out + (size_t)wid * ldo + c0) = packbf(acc0, acc1);
    } else {
        float* o = (float*)out + (size_t)wid * ldo + c0;
        if (c0 < F)     o[0] = acc0;
        if (c0 + 1 < F) o[1] = acc1;
    }
}

// F=64 bf16->bf16 gather, 2 nodes per wave (half-wave each): no idle lanes
__global__ __launch_bounds__(256) void k_gather64x2(
        const ushort* __restrict__ featb, ushort* __restrict__ out,
        const int* __restrict__ csr, const int* __restrict__ rs,
        const float* __restrict__ invdeg) {
    int w = (blockIdx.x * blockDim.x + threadIdx.x) >> 6;
    int lane = threadIdx.x & 63;
    int v = w * 2 + (lane >> 5);
    if (v >= N_NODES) return;
    int c0 = (lane & 31) * 2;
    int s0 = rs[v], s1 = rs[v + 1];
    float acc0 = 0.f, acc1 = 0.f;
    int j = s0;
    for (; j + 8 <= s1; j += 8) {
        int idx[8];
#pragma unroll
        for (int u = 0; u < 8; ++u) idx[u] = csr[j + u];
        uint d[8];
#pragma unroll
        for (int u = 0; u < 8; ++u)
            d[u] = *(const uint*)(featb + (size_t)idx[u] * 64 + c0);
#pragma unroll
        for (int u = 0; u < 8; ++u) { acc0 += bflo(d[u]); acc1 += bfhi(d[u]); }
    }
    for (; j < s1; ++j) {
        uint d = *(const uint*)(featb + (size_t)csr[j] * 64 + c0);
        acc0 += bflo(d); acc1 += bfhi(d);
    }
    float sc = invdeg[v];
    *(uint*)(out + (size_t)v * 64 + c0) = packbf(acc0 * sc, acc1 * sc);
}

// thread-per-node, F=5 fp32 (P4), unrolled by 4
__global__ __launch_bounds__(256) void k_gather5(
        const float* __restrict__ feat, float* __restrict__ out,
        const int* __restrict__ csr, const int* __restrict__ rs,
        const float* __restrict__ invdeg) {
    int v = blockIdx.x * blockDim.x + threadIdx.x;
    if (v >= N_NODES) return;
    int s0 = rs[v], s1 = rs[v + 1];
    float a[5] = {0.f, 0.f, 0.f, 0.f, 0.f};
    int j = s0;
    for (; j + 4 <= s1; j += 4) {
        const float* r0 = feat + (size_t)csr[j]     * 5;
        const float* r1 = feat + (size_t)csr[j + 1] * 5;
        const float* r2 = feat + (size_t)csr[j + 2] * 5;
        const float* r3 = feat + (size_t)csr[j + 3] * 5;
        float t0[5], t1[5], t2[5], t3[5];
#pragma unroll
        for (int c = 0; c < 5; ++c) { t0[c] = r0[c]; t1[c] = r1[c]; t2[c] = r2[c]; t3[c] = r3[c]; }
#pragma unroll
        for (int c = 0; c < 5; ++c) a[c] += (t0[c] + t1[c]) + (t2[c] + t3[c]);
    }
    for (; j < s1; ++j) {
        const float* r = feat + (size_t)csr[j] * 5;
#pragma unroll
        for (int c = 0; c < 5; ++c) a[c] += r[c];
    }
    float sc = invdeg[v];
    float* o = out + (size_t)v * 5;
#pragma unroll
    for (int c = 0; c < 5; ++c) o[c] = a[c] * sc;
}

// ------------------------------------------------------------ MFMA GEMM
// No LDS, no barriers. A bf16 [M x lda] (k-padded, pad x W-zero = 0);
// B pre-split/transposed/padded bf16 [128 x ldb]. fp32 accum, W hi+lo passes.
// Dual-A: C = act(A1@B1 + A2@B2 + bias [+ addend]).
// Block = 4 waves; wave computes rows m0+wv*32..+31, cols n0..n0+63.
// Frag maps: A row=lane&15(+16), k=(lane>>4)*8+j; B row(n)=lane&15, same k;
// D col=lane&15, row=(lane>>4)*4+r  [m89-verified].
__global__ __launch_bounds__(256) void k_mm(
        const ushort* __restrict__ A1, int lda1, int kt1,
        const ushort* __restrict__ B1hi, const ushort* __restrict__ B1lo, int ldb1,
        const ushort* __restrict__ A2, int lda2, int kt2,
        const ushort* __restrict__ B2hi, const ushort* __restrict__ B2lo, int ldb2,
        const float* __restrict__ addend, int ldadd,
        const float* __restrict__ bias,
        void* __restrict__ C, int ldc, int N, int flags)  // 1=relu, 2=bf16 out
{
    const int M = N_NODES;
    int tid = threadIdx.x;
    int wv = tid >> 6, lane = tid & 63;
    int lr = lane & 15, lg = lane >> 4, lg8 = lg * 8;
    int m0 = blockIdx.x * 128, n0 = blockIdx.y * 64;
    int r0 = m0 + wv * 32 + lr;
    int ra0 = r0 < M ? r0 : M - 1;          // clamp: results write-guarded
    int ra1 = r0 + 16 < M ? r0 + 16 : M - 1;

    f32x4 acc[2][4];
#pragma unroll
    for (int i = 0; i < 2; ++i)
#pragma unroll
        for (int n = 0; n < 4; ++n) acc[i][n] = (f32x4){0.f, 0.f, 0.f, 0.f};

#pragma unroll
    for (int pass = 0; pass < 2; ++pass) {
        const ushort* A   = pass ? A2 : A1;
        const ushort* Bhi = pass ? B2hi : B1hi;
        const ushort* Blo = pass ? B2lo : B1lo;
        int lda = pass ? lda2 : lda1;
        int ldb = pass ? ldb2 : ldb1;
        int kts = pass ? kt2 : kt1;
        if (!A) continue;
        const ushort* pA0 = A + (size_t)ra0 * lda + lg8;
        const ushort* pA1 = A + (size_t)ra1 * lda + lg8;
        const ushort* pH  = Bhi + (size_t)(n0 + lr) * ldb + lg8;
        const ushort* pL  = Blo + (size_t)(n0 + lr) * ldb + lg8;
        int nstep = 16 * ldb;
        for (int kt = 0; kt < kts; ++kt, pA0 += 32, pA1 += 32, pH += 32, pL += 32) {
            bf16x8 a0 = *(const bf16x8*)pA0;
            bf16x8 a1 = *(const bf16x8*)pA1;
#pragma unroll
            for (int nf = 0; nf < 4; ++nf) {
                bf16x8 bh = *(const bf16x8*)(pH + nf * nstep);
                bf16x8 bl = *(const bf16x8*)(pL + nf * nstep);
                acc[0][nf] = __builtin_amdgcn_mfma_f32_16x16x32_bf16(a0, bh, acc[0][nf], 0, 0, 0);
                acc[1][nf] = __builtin_amdgcn_mfma_f32_16x16x32_bf16(a1, bh, acc[1][nf], 0, 0, 0);
                acc[0][nf] = __builtin_amdgcn_mfma_f32_16x16x32_bf16(a0, bl, acc[0][nf], 0, 0, 0);
                acc[1][nf] = __builtin_amdgcn_mfma_f32_16x16x32_bf16(a1, bl, acc[1][nf], 0, 0, 0);
            }
        }
    }
    int doRelu = flags & 1, outBf = flags & 2;
#pragma unroll
    for (int mi = 0; mi < 2; ++mi) {
#pragma unroll
        for (int r = 0; r < 4; ++r) {
            int gm = m0 + wv * 32 + mi * 16 + lg * 4 + r;
            if (gm >= M) continue;
#pragma unroll
            for (int nf = 0; nf < 4; ++nf) {
                int gn = n0 + nf * 16 + lr;
                if (gn >= N) continue;
                float v = acc[mi][nf][r];
                if (bias)   v += bias[gn];
                if (addend) v += addend[(size_t)gm * ldadd + gn];
                if (doRelu) v = fmaxf(v, 0.f);
                if (outBf) ((ushort*)C)[(size_t)gm * ldc + gn] = f2bf(v);
                else       ((float*)C)[(size_t)gm * ldc + gn] = v;
            }
        }
    }
}

// ------------------------------------------------ chunked segment-sum pooling
__global__ void k_poolb(const ushort* __restrict__ featb, int ldf, const int* __restrict__ gid,
                        float* __restrict__ pool, int F) {
    int base = blockIdx.x * 256;
    if (base >= N_NODES) return;
    int end = base + 256 < N_NODES ? base + 256 : N_NODES;
    int f = threadIdx.x;  // 128 threads
    float local = 0.f;
    int curg = gid[base];
    for (int v = base; v < end; ++v) {
        int g = gid[v];
        if (g != curg) {
            if (f < F) atomicAdd(&pool[curg * F + f], local);
            local = 0.f;
            curg = g;
        }
        if (f < F) local += bf2f(featb[(size_t)v * ldf + f]);
    }
    if (f < F) atomicAdd(&pool[curg * F + f], local);
}

__global__ void k_pool(const float* __restrict__ feat, const int* __restrict__ gid,
                       float* __restrict__ pool, int F) {
    int base = blockIdx.x * 256;
    if (base >= N_NODES) return;
    int end = base + 256 < N_NODES ? base + 256 : N_NODES;
    int f = threadIdx.x;
    float local = 0.f;
    int curg = gid[base];
    for (int v = base; v < end; ++v) {
        int g = gid[v];
        if (g != curg) {
            if (f < F) atomicAdd(&pool[curg * F + f], local);
            local = 0.f;
            curg = g;
        }
        if (f < F) local += feat[(size_t)v * F + f];
    }
    if (f < F) atomicAdd(&pool[curg * F + f], local);
}

// out[g][j] = (pooledH[g]@Ws4[:,j] + cnt_g*b4[j] + pooledA[g][j]) / max(cnt_g,1)
__global__ void k_final(const float* __restrict__ pooledH, const float* __restrict__ pooledA,
                        const float* __restrict__ Ws4, const float* __restrict__ b4,
                        const int* __restrict__ gstart, float* __restrict__ out) {
    int idx = threadIdx.x;
    if (idx >= N_GRAPHS * 5) return;
    int g = idx / 5, j = idx % 5;
    float cnt = (float)(gstart[g + 1] - gstart[g]);
    float s = 0.f;
    for (int k = 0; k < 103; ++k) s += pooledH[g * 103 + k] * Ws4[k * 5 + j];
    out[idx] = (s + cnt * b4[j] + pooledA[idx]) / fmaxf(cnt, 1.0f);
}

// --------------------------------------------------------------- launcher
extern "C" void kernel_launch(void* const* d_in, const int* in_sizes, int n_in,
                              void* d_out, int out_size, void* d_ws, size_t ws_size,
                              hipStream_t stream) {
    const float* x   = (const float*)d_in[0];
    const int*   src = (const int*)d_in[1];
    const int*   dst = (const int*)d_in[2];
    const int*   gid = (const int*)d_in[3];
    const float* Ws1 = (const float*)d_in[4],  *Wn1 = (const float*)d_in[5],  *b1 = (const float*)d_in[6];
    const float* Ws2 = (const float*)d_in[7],  *Wn2 = (const float*)d_in[8],  *b2 = (const float*)d_in[9];
    const float* Ws3 = (const float*)d_in[10], *Wn3 = (const float*)d_in[11], *b3 = (const float*)d_in[12];
    const float* Ws4 = (const float*)d_in[13], *Wn4 = (const float*)d_in[14], *b4 = (const float*)d_in[15];
    float* out = (float*)d_out;

    char* ws = (char*)d_ws;
    size_t off = 0;
    auto alloc = [&](size_t bytes) -> void* {
        void* p = ws + off;
        off += (bytes + 255) & ~(size_t)255;
        return p;
    };
    ushort* xb   = (ushort*)alloc((size_t)N_NODES * 64 * 2);
    ushort* agg1 = (ushort*)alloc((size_t)N_NODES * 64 * 2);
    ushort* S1   = (ushort*)alloc((size_t)N_NODES * 128 * 2);  // h1
    ushort* S2   = (ushort*)alloc((size_t)N_NODES * 128 * 2);  // h3
    ushort* S3   = (ushort*)alloc((size_t)N_NODES * 128 * 2);  // h2
    ushort* aggB = (ushort*)alloc((size_t)N_NODES * 128 * 2);  // agg(h1)/agg(h2) bf16
    float*  P4   = (float*) alloc((size_t)N_NODES * 5 * 4);
    float*  agg4 = (float*) alloc((size_t)N_NODES * 5 * 4);
    int*   csr     = (int*)  alloc((size_t)N_EDGES * 4);
    int*   rank    = (int*)  alloc((size_t)N_EDGES * 4);
    int*   rs      = (int*)  alloc((size_t)(N_NODES + 1) * 4);
    int*   count   = (int*)  alloc((size_t)N_NODES * 4);
    int*   partials= (int*)  alloc(128 * 4);
    float* invdeg  = (float*)alloc((size_t)N_NODES * 4);
    int*   gstart  = (int*)  alloc((N_GRAPHS + 1) * 4);
    float* pooledH = (float*)alloc(N_GRAPHS * 103 * 4);
    float* pooledA = (float*)alloc(N_GRAPHS * 5 * 4);
    // weight tables: [128][Kp] bf16 hi/lo each
    auto walloc = [&](int Kp) { return (ushort*)alloc((size_t)128 * Kp * 2); };
    ushort *Ws1h = walloc(64),  *Ws1l = walloc(64);
    ushort *Wn1h = walloc(64),  *Wn1l = walloc(64);
    ushort *Wn2h = walloc(128), *Wn2l = walloc(128);
    ushort *Ws2h = walloc(128), *Ws2l = walloc(128);
    ushort *Wn3h = walloc(128), *Wn3l = walloc(128);
    ushort *Ws3h = walloc(128), *Ws3l = walloc(128);
    ushort *Wn4h = walloc(128), *Wn4l = walloc(128);

    hipMemsetAsync(count, 0, (size_t)N_NODES * 4, stream);
    hipMemsetAsync(pooledH, 0, N_GRAPHS * 103 * 4, stream);
    hipMemsetAsync(pooledA, 0, N_GRAPHS * 5 * 4, stream);

    WJobs jobs = {{
        {Ws1, Ws1h, Ws1l, 64, 128, 64},
        {Wn1, Wn1h, Wn1l, 64, 128, 64},
        {Wn2, Wn2h, Wn2l, 128, 118, 128},
        {Ws2, Ws2h, Ws2l, 128, 118, 128},
        {Wn3, Wn3h, Wn3l, 118, 103, 128},
        {Ws3, Ws3h, Ws3l, 118, 103, 128},
        {Wn4, Wn4h, Wn4l, 103, 5, 128},
    }};
    k_wsplit<<<dim3(64, 7), 256, 0, stream>>>(jobs);
    k_tobf16<<<(N_NODES * 64 / 4 + 255) / 256, 256, 0, stream>>>(x, xb, N_NODES * 64);

    const int SCAN_BLOCKS = (N_NODES + 1023) / 1024;  // 98
    k_countrank<<<(N_EDGES + 255) / 256, 256, 0, stream>>>(dst, count, rank);
    k_scan1<<<SCAN_BLOCKS, 256, 0, stream>>>(count, rs, partials);
    k_scan2<<<1, 128, 0, stream>>>(partials, SCAN_BLOCKS);
    k_scan3<<<SCAN_BLOCKS, 256, 0, stream>>>(rs, partials);
    k_invdeg<<<(N_NODES + 255) / 256, 256, 0, stream>>>(count, invdeg);
    k_gbounds<<<1, 128, 0, stream>>>(gid, gstart);
    k_scatter<<<(N_EDGES + 255) / 256, 256, 0, stream>>>(src, dst, rank, rs, csr);

    const int GATHER_BLOCKS = (N_NODES * 64 + 255) / 256;       // wave per node
    const int GATHER2_BLOCKS = (N_NODES * 32 + 255) / 256;      // 2 nodes/wave
    dim3 mm2((N_NODES + 127) / 128, 2);
    dim3 mm1((N_NODES + 127) / 128, 1);
    const int POOL_BLOCKS = (N_NODES + 255) / 256;

    // layer 1: agg(x) (2 nodes/wave); h1 = relu(x@Ws1 + agg@Wn1 + b1) -> S1
    k_gather64x2<<<GATHER2_BLOCKS, 256, 0, stream>>>(xb, agg1, csr, rs, invdeg);
    k_mm<<<mm2, 256, 0, stream>>>(xb, 64, 2, Ws1h, Ws1l, 64,
                                  agg1, 64, 2, Wn1h, Wn1l, 64,
                                  nullptr, 0, b1, S1, 128, 128, 1 | 2);

    // layer 2 (agg-then-project): agg(h1) -> aggB; h2 = relu(h1@Ws2 + aggB@Wn2 + b2) -> S3
    k_gatherb<<<GATHER_BLOCKS, 256, 0, stream>>>(S1, 128, aggB, 128, 1, csr, rs, invdeg, 128);
    k_mm<<<mm2, 256, 0, stream>>>(S1, 128, 4, Ws2h, Ws2l, 128,
                                  aggB, 128, 4, Wn2h, Wn2l, 128,
                                  nullptr, 0, b2, S3, 128, 118, 1 | 2);

    // layer 3 (agg-then-project): agg(h2) -> aggB; h3 = relu(h2@Ws3 + aggB@Wn3 + b3) -> S2
    k_gatherb<<<GATHER_BLOCKS, 256, 0, stream>>>(S3, 128, aggB, 128, 1, csr, rs, invdeg, 118);
    k_mm<<<mm2, 256, 0, stream>>>(S3, 128, 4, Ws3h, Ws3l, 128,
                                  aggB, 128, 4, Wn3h, Wn3l, 128,
                                  nullptr, 0, b3, S2, 128, 103, 1 | 2);

    // layer 4 (project-then-agg at F=5): P4 = h3@Wn4; agg5; pooling + finalize
    k_mm<<<mm1, 256, 0, stream>>>(S2, 128, 4, Wn4h, Wn4l, 128,
                                  nullptr, 0, 0, nullptr, nullptr, 0,
                                  nullptr, 0, nullptr, P4, 5, 5, 0);
    k_gather5<<<(N_NODES + 255) / 256, 256, 0, stream>>>(P4, agg4, csr, rs, invdeg);

    k_poolb<<<POOL_BLOCKS, 128, 0, stream>>>(S2, 128, gid, pooledH, 103);
    k_pool<<<POOL_BLOCKS, 128, 0, stream>>>(agg4, gid, pooledA, 5);
    k_final<<<1, 320, 0, stream>>>(pooledH, pooledA, Ws4, b4, gstart, out);
}